// Round 10
// baseline (557.467 us; speedup 1.0000x reference)
//
#include <hip/hip_runtime.h>
#include <math.h>

#define HID 1024
#define SLOT 256
#define EMB 256
#define ACT 128
#define NCODE 1024
#define R_ROWS 49152
#define M_ROWS 47616

// output offsets (float elements)
#define OFF_AD 0
#define OFF_Z  12189696
#define OFF_AV 18284544
#define OFF_QS 24379392
#define OFF_IDX 30474240
#define OFF_QL 30521856
#define OFF_CL 30521857

typedef _Float16 f16x8 __attribute__((ext_vector_type(8)));
typedef float f32x4 __attribute__((ext_vector_type(4)));

// ---------------- fused pack kernel ----------------
__device__ __forceinline__ void pack_body(
    const float* __restrict__ W, _Float16* __restrict__ hi, _Float16* __restrict__ lo,
    int lgS, int N, int p, const float* __restrict__ scale)
{
    int j = p & 7;
    int l = (p >> 3) & 63;
    int q = p >> 9;
    int s = q & ((1 << lgS) - 1);
    int t = q >> lgS;
    int n = t * 16 + (l & 15);
    int k = s * 32 + ((l >> 4) << 3) + j;
    float x = W[(size_t)k * N + n];
    if (scale) x *= scale[k];
    _Float16 h = (_Float16)x;
    hi[p] = h;
    lo[p] = (_Float16)(x - (float)h);
}

__global__ __launch_bounds__(256) void k_packall(
    const float* __restrict__ W1, const float* __restrict__ W2,
    const float* __restrict__ Wm, const float* __restrict__ Wv,
    const float* __restrict__ CB, const float* __restrict__ ln_g,
    const float* __restrict__ ln_b, const float* __restrict__ b2,
    _Float16* __restrict__ W1h, _Float16* __restrict__ W1l,
    _Float16* __restrict__ W2h, _Float16* __restrict__ W2l,
    _Float16* __restrict__ Wmh, _Float16* __restrict__ Wml,
    _Float16* __restrict__ Wvh, _Float16* __restrict__ Wvl,
    _Float16* __restrict__ CBh, _Float16* __restrict__ CBl,
    float* __restrict__ cn, float* __restrict__ v0, float* __restrict__ v1,
    float* __restrict__ losss)
{
    const int bi = blockIdx.x;
    const int tid = threadIdx.x;
    if (bi == 0 && tid == 0) *losss = 0.f;

    if (bi < 1024) {
        pack_body(W1, W1h, W1l, 3, HID, bi * 256 + tid, (const float*)0);
    } else if (bi < 2048) {
        pack_body(W2, W2h, W2l, 5, EMB, (bi - 1024) * 256 + tid, ln_g);
    } else if (bi < 2176) {
        pack_body(Wm, Wmh, Wml, 3, ACT, (bi - 2048) * 256 + tid, (const float*)0);
    } else if (bi < 2304) {
        pack_body(Wv, Wvh, Wvl, 3, ACT, (bi - 2176) * 256 + tid, (const float*)0);
    } else if (bi < 2816) {
        int p = (bi - 2304) * 256 + tid;
        int j = p & 7;
        int l = (p >> 3) & 63;
        int q = p >> 9;
        int s = q & 7;
        int t = q >> 3;
        int n = t * 32 + (l & 31);
        int k = s * 16 + ((l >> 5) << 3) + j;
        float x = CB[(size_t)n * ACT + k];
        _Float16 h = (_Float16)x;
        CBh[p] = h;
        CBl[p] = (_Float16)(x - (float)h);
    } else if (bi < 2820) {
        int c = (bi - 2816) * 256 + tid;
        float s = 0.f;
        #pragma unroll
        for (int k = 0; k < ACT; k += 4) {
            float4 v = *(const float4*)&CB[(size_t)c * ACT + k];
            s += v.x*v.x + v.y*v.y + v.z*v.z + v.w*v.w;
        }
        cn[c] = s;
    } else {
        int n = tid;
        float a0 = 0.f, a1 = 0.f;
        for (int c = 0; c < HID; ++c) {
            float w2 = W2[(size_t)c * EMB + n];
            a1 = fmaf(ln_g[c], w2, a1);
            a0 = fmaf(ln_b[c], w2, a0);
        }
        v1[n] = a1;
        v0[n] = a0 + b2[n];
    }
}

// ---------------- K1: GEMM1 — 256-row blocks, 2 row-tiles/wave ----------------
// grid: (RC/256) row-groups x 16 col-panels
__global__ __launch_bounds__(512, 2) void k_gemm1(
    const float* __restrict__ X, const float* __restrict__ b1,
    const _Float16* __restrict__ W1h, const _Float16* __restrict__ W1l,
    _Float16* __restrict__ GHh, _Float16* __restrict__ GHl,
    float* __restrict__ stats, int row0)
{
    __shared__ _Float16 sh[32768];   // W panel hi [0,16384) lo [16384,32768); then h-bounce (64 KB)

    const int tid = threadIdx.x;
    const int w = tid >> 6, l = tid & 63, lr = l & 15, lg = l >> 4;
    const int p = blockIdx.x & 15;
    const int rg = blockIdx.x >> 4;
    const int rowc = rg * 256;

    // stage W panel (64 KB)
    {
        const float4* s0 = (const float4*)(W1h + (size_t)p * 16384);
        const float4* s1 = (const float4*)(W1l + (size_t)p * 16384);
        float4* d = (float4*)sh;
        #pragma unroll
        for (int i = 0; i < 4; ++i) {
            d[tid + 512 * i] = s0[tid + 512 * i];
            d[2048 + tid + 512 * i] = s1[tid + 512 * i];
        }
    }

    // A fragments: 2 row-tiles (32 rows) per wave
    f16x8 a0[2][8], a1[2][8];
    #pragma unroll
    for (int rt = 0; rt < 2; ++rt) {
        const float* xrow = X + (size_t)(row0 + rowc + w * 32 + rt * 16 + lr) * SLOT + lg * 8;
        #pragma unroll
        for (int s = 0; s < 8; ++s) {
            float4 xa = *(const float4*)(xrow + 32 * s);
            float4 xb = *(const float4*)(xrow + 32 * s + 4);
            float xv[8] = {xa.x, xa.y, xa.z, xa.w, xb.x, xb.y, xb.z, xb.w};
            #pragma unroll
            for (int e = 0; e < 8; ++e) {
                _Float16 h = (_Float16)xv[e];
                a0[rt][s][e] = h;
                a1[rt][s][e] = (_Float16)(xv[e] - (float)h);
            }
        }
    }
    __syncthreads();

    f32x4 acc[2][4];
    #pragma unroll
    for (int rt = 0; rt < 2; ++rt)
        #pragma unroll
        for (int t = 0; t < 4; ++t) acc[rt][t] = (f32x4){0.f, 0.f, 0.f, 0.f};

    #pragma unroll
    for (int s = 0; s < 8; ++s) {
        #pragma unroll
        for (int t = 0; t < 4; ++t) {
            f16x8 bh = *(const f16x8*)&sh[((t * 8 + s) * 64 + l) * 8];
            f16x8 bl = *(const f16x8*)&sh[16384 + ((t * 8 + s) * 64 + l) * 8];
            #pragma unroll
            for (int rt = 0; rt < 2; ++rt) {
                acc[rt][t] = __builtin_amdgcn_mfma_f32_16x16x32_f16(a0[rt][s], bh, acc[rt][t], 0, 0, 0);
                acc[rt][t] = __builtin_amdgcn_mfma_f32_16x16x32_f16(a0[rt][s], bl, acc[rt][t], 0, 0, 0);
                acc[rt][t] = __builtin_amdgcn_mfma_f32_16x16x32_f16(a1[rt][s], bh, acc[rt][t], 0, 0, 0);
            }
        }
    }

    // bias + relu
    #pragma unroll
    for (int rt = 0; rt < 2; ++rt)
        #pragma unroll
        for (int t = 0; t < 4; ++t) {
            float bb = b1[p * 64 + t * 16 + lr];
            #pragma unroll
            for (int r = 0; r < 4; ++r) acc[rt][t][r] = fmaxf(acc[rt][t][r] + bb, 0.f);
        }

    // LN partial stats per row-tile
    #pragma unroll
    for (int rt = 0; rt < 2; ++rt) {
        float sum[4] = {0,0,0,0}, sq[4] = {0,0,0,0};
        #pragma unroll
        for (int t = 0; t < 4; ++t)
            #pragma unroll
            for (int r = 0; r < 4; ++r) {
                float v = acc[rt][t][r];
                sum[r] += v; sq[r] = fmaf(v, v, sq[r]);
            }
        #pragma unroll
        for (int off = 1; off < 16; off <<= 1)
            #pragma unroll
            for (int r = 0; r < 4; ++r) {
                sum[r] += __shfl_xor(sum[r], off, 64);
                sq[r]  += __shfl_xor(sq[r],  off, 64);
            }
        if (lr == 0) {
            #pragma unroll
            for (int r = 0; r < 4; ++r) {
                size_t grow = (size_t)row0 + rowc + w * 32 + rt * 16 + lg * 4 + r;
                float2 st = {sum[r], sq[r]};
                *(float2*)&stats[((size_t)p * R_ROWS + grow) * 2] = st;
            }
        }
    }
    __syncthreads();   // W panel reads done

    // bounce raw h (hi/lo) into LDS, swizzled (256 rows x 64 cols = 64 KB)
    #pragma unroll
    for (int rt = 0; rt < 2; ++rt)
        #pragma unroll
        for (int t = 0; t < 4; ++t) {
            #pragma unroll
            for (int r = 0; r < 4; ++r) {
                int rowloc = w * 32 + rt * 16 + lg * 4 + r;
                int col = t * 16 + lr;
                int cc = col >> 3, j = col & 7;
                int ad = rowloc * 64 + ((cc ^ (rowloc & 7)) << 3) + j;
                float v = acc[rt][t][r];
                _Float16 h = (_Float16)v;
                sh[ad] = h;
                sh[16384 + ad] = (_Float16)(v - (float)h);
            }
        }
    __syncthreads();

    // fragment-linear store: 2048 f16x8 units per array
    #pragma unroll
    for (int i = 0; i < 4; ++i) {
        int u = tid + 512 * i;               // 0..2047
        int RTl = u >> 7;                    // 0..15
        int Sl  = (u >> 6) & 1;
        int li  = u & 63;
        int row = RTl * 16 + (li & 15);
        int cc  = Sl * 4 + (li >> 4);
        int ad  = row * 64 + ((cc ^ (row & 7)) << 3);
        f16x8 vh = *(const f16x8*)&sh[ad];
        f16x8 vl = *(const f16x8*)&sh[16384 + ad];
        size_t RTg = (size_t)rg * 16 + RTl;
        size_t off = ((RTg * 32 + (2 * p + Sl)) * 64 + li) * 8;
        *(f16x8*)&GHh[off] = vh;
        *(f16x8*)&GHl[off] = vl;
    }
}

// ---------------- K2: GEMM2 + LN-fold + heads — 2rt x 4t waves ----------------
// grid: RC/64 blocks; 8 waves = 2 row-halves x 4 col-quarters
__global__ __launch_bounds__(512, 4) void k_gemm2(
    const _Float16* __restrict__ GHh, const _Float16* __restrict__ GHl,
    const _Float16* __restrict__ W2h, const _Float16* __restrict__ W2l,
    const _Float16* __restrict__ Wmh, const _Float16* __restrict__ Wml,
    const _Float16* __restrict__ Wvh, const _Float16* __restrict__ Wvl,
    const float* __restrict__ stats, const float* __restrict__ v0,
    const float* __restrict__ v1, const float* __restrict__ bm,
    const float* __restrict__ bv,
    float* __restrict__ MT, float* __restrict__ VT, int row0)
{
    __shared__ _Float16 sh[32768];
    __shared__ float mu_s[64], rs_s[64];

    const int tid = threadIdx.x;
    const int w = tid >> 6, l = tid & 63, lr = l & 15, lg = l >> 4;
    const int rh = w >> 2, cg = w & 3;
    const int rb = blockIdx.x;
    const size_t grow0 = (size_t)row0 + rb * 64;

    if (tid < 64) {
        float s = 0.f, q = 0.f;
        #pragma unroll
        for (int pp = 0; pp < 16; ++pp) {
            float2 st = *(const float2*)&stats[((size_t)pp * R_ROWS + grow0 + tid) * 2];
            s += st.x; q += st.y;
        }
        float mu = s * (1.f / HID);
        float var = q * (1.f / HID) - mu * mu;
        mu_s[tid] = mu;
        rs_s[tid] = 1.f / sqrtf(var + 1e-5f);
    }

    float v0r[4], v1r[4];
    #pragma unroll
    for (int t = 0; t < 4; ++t) {
        int n = cg * 64 + t * 16 + lr;
        v0r[t] = v0[n];
        v1r[t] = v1[n];
    }

    f32x4 acc[2][4];
    #pragma unroll
    for (int rt = 0; rt < 2; ++rt)
        #pragma unroll
        for (int t = 0; t < 4; ++t) acc[rt][t] = (f32x4){0.f, 0.f, 0.f, 0.f};

    for (int kp = 0; kp < 8; ++kp) {
        __syncthreads();
        #pragma unroll
        for (int i = 0; i < 4; ++i) {
            int u = tid + 512 * i;
            int arr = u >> 10;
            int ui = u & 1023;
            int RTl = ui >> 8;
            int rem = ui & 255;
            size_t gu = ((size_t)(rb * 4 + RTl) * 32 + kp * 4) * 64 + rem;
            const _Float16* src = arr ? GHl : GHh;
            *(f16x8*)&sh[(size_t)arr * 8192 + (size_t)ui * 8] = *(const f16x8*)&src[gu * 8];
        }
        __syncthreads();

        #pragma unroll
        for (int sl = 0; sl < 4; ++sl) {
            f16x8 bh[4], bl[4];
            #pragma unroll
            for (int t = 0; t < 4; ++t) {
                int tg = cg * 4 + t;
                size_t o = ((size_t)(tg * 32 + kp * 4 + sl) * 64 + l) * 8;
                bh[t] = *(const f16x8*)&W2h[o];
                bl[t] = *(const f16x8*)&W2l[o];
            }
            #pragma unroll
            for (int rt = 0; rt < 2; ++rt) {
                int RT = rh * 2 + rt;
                f16x8 ah = *(const f16x8*)&sh[((RT * 4 + sl) * 64 + l) * 8];
                f16x8 al = *(const f16x8*)&sh[8192 + ((RT * 4 + sl) * 64 + l) * 8];
                #pragma unroll
                for (int t = 0; t < 4; ++t) {
                    acc[rt][t] = __builtin_amdgcn_mfma_f32_16x16x32_f16(ah, bh[t], acc[rt][t], 0, 0, 0);
                    acc[rt][t] = __builtin_amdgcn_mfma_f32_16x16x32_f16(ah, bl[t], acc[rt][t], 0, 0, 0);
                    acc[rt][t] = __builtin_amdgcn_mfma_f32_16x16x32_f16(al, bh[t], acc[rt][t], 0, 0, 0);
                }
            }
        }
    }
    __syncthreads();

    // E epilogue with LN-fold; write E hi/lo swizzled (64 rows x 256 cols)
    #pragma unroll
    for (int rt = 0; rt < 2; ++rt) {
        #pragma unroll
        for (int t = 0; t < 4; ++t) {
            int n = cg * 64 + t * 16 + lr;
            int cc = n >> 3, j = n & 7;
            #pragma unroll
            for (int r = 0; r < 4; ++r) {
                int row = rh * 32 + rt * 16 + lg * 4 + r;
                float mu = mu_s[row], rs = rs_s[row];
                float e = rs * acc[rt][t][r] - rs * mu * v1r[t] + v0r[t];
                _Float16 h = (_Float16)e;
                int ad = row * 256 + ((cc ^ (row & 7)) << 3) + j;
                sh[ad] = h;
                sh[16384 + ad] = (_Float16)(e - (float)h);
            }
        }
    }
    __syncthreads();

    // heads: waves 0..3 -> MT, 4..7 -> VT; wave covers 64 rows x 32 head-cols
    const _Float16* WXh = (w < 4) ? Wmh : Wvh;
    const _Float16* WXl = (w < 4) ? Wml : Wvl;
    f32x4 acc3[4][2];
    #pragma unroll
    for (int rt = 0; rt < 4; ++rt)
        #pragma unroll
        for (int t = 0; t < 2; ++t) acc3[rt][t] = (f32x4){0.f, 0.f, 0.f, 0.f};

    #pragma unroll
    for (int s = 0; s < 8; ++s) {
        f16x8 bh[2], bl[2];
        #pragma unroll
        for (int t = 0; t < 2; ++t) {
            int tg = (w & 3) * 2 + t;
            size_t o = ((size_t)(tg * 8 + s) * 64 + l) * 8;
            bh[t] = *(const f16x8*)&WXh[o];
            bl[t] = *(const f16x8*)&WXl[o];
        }
        #pragma unroll
        for (int rt = 0; rt < 4; ++rt) {
            int row = rt * 16 + lr;
            int cc = s * 4 + lg;
            int ad = row * 256 + ((cc ^ (row & 7)) << 3);
            f16x8 ah = *(const f16x8*)&sh[ad];
            f16x8 al = *(const f16x8*)&sh[16384 + ad];
            #pragma unroll
            for (int t = 0; t < 2; ++t) {
                acc3[rt][t] = __builtin_amdgcn_mfma_f32_16x16x32_f16(ah, bh[t], acc3[rt][t], 0, 0, 0);
                acc3[rt][t] = __builtin_amdgcn_mfma_f32_16x16x32_f16(ah, bl[t], acc3[rt][t], 0, 0, 0);
                acc3[rt][t] = __builtin_amdgcn_mfma_f32_16x16x32_f16(al, bh[t], acc3[rt][t], 0, 0, 0);
            }
        }
    }

    #pragma unroll
    for (int rt = 0; rt < 4; ++rt) {
        #pragma unroll
        for (int t = 0; t < 2; ++t) {
            int a = (w & 3) * 32 + t * 16 + lr;
            float bx = (w < 4) ? bm[a] : bv[a];
            #pragma unroll
            for (int r = 0; r < 4; ++r) {
                size_t grow = grow0 + rt * 16 + lg * 4 + r;
                float vv = acc3[rt][t][r] + bx;
                if (w < 4) MT[grow * ACT + a] = vv;
                else       VT[grow * ACT + a] = fabsf(vv);
            }
        }
    }
}

// ---------------- fused action + VQ + finalize (unchanged from R9) ------------
__global__ __launch_bounds__(256, 3) void k_vq32(
    const float* __restrict__ MT, const float* __restrict__ VT,
    const float* __restrict__ noise,
    const _Float16* __restrict__ CBh, const _Float16* __restrict__ CBl,
    const float* __restrict__ cn, const float* __restrict__ CB,
    float* __restrict__ out, float* __restrict__ losss)
{
    typedef float f32x16 __attribute__((ext_vector_type(16)));
    __shared__ _Float16 Zh[32 * 128];
    __shared__ _Float16 Zl[32 * 128];
    __shared__ float pb[4][32];
    __shared__ int   pi[4][32];
    __shared__ int   idx_s[32];
    __shared__ float red[4];

    const int tid = threadIdx.x;
    const int rowbase = blockIdx.x * 32;
    const int a = tid & 127;
    const int rhalf = tid >> 7;
    const int ga = a >> 3, ja = a & 7;

    for (int g = 0; g < 2; ++g) {
        float m1v[8], m2v[8], v1v[8], v2v[8], nzv[8];
        #pragma unroll
        for (int i = 0; i < 8; ++i) {
            int row = g * 16 + 2 * i + rhalf;
            int m = rowbase + row;
            int b = m / 372;
            int r1 = m + 12 * b;
            int r2 = r1 + 12;
            m1v[i] = MT[(size_t)r1 * ACT + a];
            m2v[i] = MT[(size_t)r2 * ACT + a];
            v1v[i] = VT[(size_t)r1 * ACT + a];
            v2v[i] = VT[(size_t)r2 * ACT + a];
            nzv[i] = noise[(size_t)m * ACT + a];
        }
        #pragma unroll
        for (int i = 0; i < 8; ++i) {
            int row = g * 16 + 2 * i + rhalf;
            int m = rowbase + row;
            float adm = m2v[i] - m1v[i];
            float adv = v2v[i] + v1v[i];
            float z = nzv[i] * sqrtf(adv + 1e-6f) + adm;
            int np = m / 12, s = m - np * 12;
            out[OFF_AD + (size_t)(np * 24 + s) * ACT + a] = adm;
            out[OFF_AD + (size_t)(np * 24 + 12 + s) * ACT + a] = adv;
            out[OFF_Z + (size_t)m * ACT + a] = z;
            _Float16 h = (_Float16)z;
            int ad = row * 128 + (((ga ^ (row & 15))) << 3) + ja;
            Zh[ad] = h;
            Zl[ad] = (_Float16)(z - (float)h);
        }
    }
    __syncthreads();

    const int w = tid >> 6, l = tid & 63;
    const int col = l & 31, hw = l >> 5;

    float best[16];
    int bidx[16];
    #pragma unroll
    for (int r = 0; r < 16; ++r) { best[r] = 3.4e38f; bidx[r] = 0; }

    for (int cc2 = 0; cc2 < 2; ++cc2) {
        f32x16 acc[4];
        #pragma unroll
        for (int t = 0; t < 4; ++t)
            #pragma unroll
            for (int r = 0; r < 16; ++r) acc[t][r] = 0.f;

        #pragma unroll
        for (int s = 0; s < 8; ++s) {
            int ad = col * 128 + (((s * 2 + hw) ^ (col & 15)) << 3);
            f16x8 ah = *(const f16x8*)&Zh[ad];
            f16x8 al = *(const f16x8*)&Zl[ad];
            #pragma unroll
            for (int t = 0; t < 4; ++t) {
                int tg = w * 8 + cc2 * 4 + t;
                f16x8 bh = *(const f16x8*)(CBh + ((size_t)(tg * 8 + s) * 64 + l) * 8);
                f16x8 bl = *(const f16x8*)(CBl + ((size_t)(tg * 8 + s) * 64 + l) * 8);
                acc[t] = __builtin_amdgcn_mfma_f32_32x32x16_f16(ah, bh, acc[t], 0, 0, 0);
                acc[t] = __builtin_amdgcn_mfma_f32_32x32x16_f16(ah, bl, acc[t], 0, 0, 0);
                acc[t] = __builtin_amdgcn_mfma_f32_32x32x16_f16(al, bh, acc[t], 0, 0, 0);
            }
        }

        float cnv[4];
        #pragma unroll
        for (int t = 0; t < 4; ++t) cnv[t] = cn[(w * 8 + cc2 * 4 + t) * 32 + col];

        #pragma unroll
        for (int reg = 0; reg < 16; ++reg) {
            #pragma unroll
            for (int t = 0; t < 4; ++t) {
                float d = cnv[t] - 2.f * acc[t][reg];
                int gi = (w * 8 + cc2 * 4 + t) * 32 + col;
                if (d < best[reg]) { best[reg] = d; bidx[reg] = gi; }
            }
        }
    }

    #pragma unroll
    for (int reg = 0; reg < 16; ++reg) {
        float bv_ = best[reg];
        int bi_ = bidx[reg];
        #pragma unroll
        for (int off = 1; off < 32; off <<= 1) {
            float ov = __shfl_xor(bv_, off, 64);
            int   oi = __shfl_xor(bi_, off, 64);
            if (ov < bv_ || (ov == bv_ && oi < bi_)) { bv_ = ov; bi_ = oi; }
        }
        if (col == 0) {
            int mrow = (reg & 3) + 8 * (reg >> 2) + 4 * hw;
            pb[w][mrow] = bv_;
            pi[w][mrow] = bi_;
        }
    }
    __syncthreads();

    if (tid < 32) {
        float bb = pb[0][tid];
        int bi_ = pi[0][tid];
        #pragma unroll
        for (int w2 = 1; w2 < 4; ++w2) {
            float v = pb[w2][tid];
            int ii = pi[w2][tid];
            if (v < bb || (v == bb && ii < bi_)) { bb = v; bi_ = ii; }
        }
        idx_s[tid] = bi_;
        out[OFF_IDX + rowbase + tid] = (float)bi_;
    }
    __syncthreads();

    float ls = 0.f;
    for (int g = 0; g < 2; ++g) {
        int civ[8]; float zv[8], qv[8];
        #pragma unroll
        for (int i = 0; i < 8; ++i) {
            int row = g * 16 + 2 * i + rhalf;
            civ[i] = idx_s[row];
            int ad = row * 128 + (((ga ^ (row & 15))) << 3) + ja;
            zv[i] = (float)Zh[ad] + (float)Zl[ad];
        }
        #pragma unroll
        for (int i = 0; i < 8; ++i) qv[i] = CB[(size_t)civ[i] * ACT + a];
        #pragma unroll
        for (int i = 0; i < 8; ++i) {
            int row = g * 16 + 2 * i + rhalf;
            size_t m = (size_t)(rowbase + row);
            float diff = zv[i] - qv[i];
            out[OFF_QS + m * ACT + a] = zv[i] + (qv[i] - zv[i]);
            out[OFF_AV + m * ACT + a] = diff;
            ls = fmaf(diff, diff, ls);
        }
    }
    #pragma unroll
    for (int off = 32; off; off >>= 1) ls += __shfl_xor(ls, off, 64);
    if (l == 0) red[w] = ls;
    __syncthreads();
    if (tid == 0) atomicAdd(losss, red[0] + red[1] + red[2] + red[3]);
}

__global__ void k_losses(const float* __restrict__ losss, float* __restrict__ out)
{
    float v = *losss * (1.f / 6094848.f);
    out[OFF_QL] = v;
    out[OFF_CL] = v;
}

extern "C" void kernel_launch(void* const* d_in, const int* in_sizes, int n_in,
                              void* d_out, int out_size, void* d_ws, size_t ws_size,
                              hipStream_t stream)
{
    const float* slots = (const float*)d_in[0];
    const float* noise = (const float*)d_in[1];
    const float* W1    = (const float*)d_in[2];
    const float* b1    = (const float*)d_in[3];
    const float* ln_g  = (const float*)d_in[4];
    const float* ln_b  = (const float*)d_in[5];
    const float* W2    = (const float*)d_in[6];
    const float* b2    = (const float*)d_in[7];
    const float* Wm    = (const float*)d_in[8];
    const float* bm    = (const float*)d_in[9];
    const float* Wv    = (const float*)d_in[10];
    const float* bv    = (const float*)d_in[11];
    const float* CB    = (const float*)d_in[12];
    float* out = (float*)d_out;
    float* ws  = (float*)d_ws;

    size_t ws_floats = ws_size / 4;
    int nchunk = (ws_floats >= 41000000) ? 2 : 4;
    int RC = R_ROWS / nchunk;

    _Float16* GHh = (_Float16*)ws;
    _Float16* GHl = (_Float16*)(ws + (size_t)RC * 512);
    float* MT = ws + (size_t)RC * 1024;
    float* VT = MT + 6291456;
    float* wb = VT + 6291456;
    _Float16* W1h = (_Float16*)(wb + 0);
    _Float16* W1l = (_Float16*)(wb + 131072);
    _Float16* W2h = (_Float16*)(wb + 262144);
    _Float16* W2l = (_Float16*)(wb + 393216);
    _Float16* Wmh = (_Float16*)(wb + 524288);
    _Float16* Wml = (_Float16*)(wb + 540672);
    _Float16* Wvh = (_Float16*)(wb + 557056);
    _Float16* Wvl = (_Float16*)(wb + 573440);
    _Float16* CBh = (_Float16*)(wb + 589824);
    _Float16* CBl = (_Float16*)(wb + 655360);
    float* cn    = wb + 720896;
    float* v0    = wb + 721920;
    float* v1    = wb + 722176;
    float* losss = wb + 722432;
    float* stats = wb + 722688;

    hipLaunchKernelGGL(k_packall, dim3(2821), dim3(256), 0, stream,
                       W1, W2, Wm, Wv, CB, ln_g, ln_b, b2,
                       W1h, W1l, W2h, W2l, Wmh, Wml, Wvh, Wvl, CBh, CBl,
                       cn, v0, v1, losss);

    for (int c = 0; c < nchunk; ++c) {
        int row0 = c * RC;
        hipLaunchKernelGGL(k_gemm1, dim3((RC / 256) * 16), dim3(512), 0, stream,
                           slots, b1, W1h, W1l, GHh, GHl, stats, row0);
        hipLaunchKernelGGL(k_gemm2, dim3(RC / 64), dim3(512), 0, stream,
                           GHh, GHl, W2h, W2l, Wmh, Wml, Wvh, Wvl,
                           stats, v0, v1, bm, bv, MT, VT, row0);
    }

    hipLaunchKernelGGL(k_vq32, dim3(M_ROWS / 32), dim3(256), 0, stream,
                       MT, VT, noise, CBh, CBl, cn, CB, out, losss);
    hipLaunchKernelGGL(k_losses, dim3(1), dim3(1), 0, stream, losss, out);
}

// Round 11
// 528.823 us; speedup vs baseline: 1.0542x; 1.0542x over previous
//
#include <hip/hip_runtime.h>
#include <math.h>

#define HID 1024
#define SLOT 256
#define EMB 256
#define ACT 128
#define NCODE 1024
#define R_ROWS 49152
#define M_ROWS 47616

// output offsets (float elements)
#define OFF_AD 0
#define OFF_Z  12189696
#define OFF_AV 18284544
#define OFF_QS 24379392
#define OFF_IDX 30474240
#define OFF_QL 30521856
#define OFF_CL 30521857

typedef _Float16 f16x8 __attribute__((ext_vector_type(8)));
typedef float f32x4 __attribute__((ext_vector_type(4)));

// ---------------- fused pack kernel ----------------
__device__ __forceinline__ void pack_body(
    const float* __restrict__ W, _Float16* __restrict__ hi, _Float16* __restrict__ lo,
    int lgS, int N, int p, const float* __restrict__ scale)
{
    int j = p & 7;
    int l = (p >> 3) & 63;
    int q = p >> 9;
    int s = q & ((1 << lgS) - 1);
    int t = q >> lgS;
    int n = t * 16 + (l & 15);
    int k = s * 32 + ((l >> 4) << 3) + j;
    float x = W[(size_t)k * N + n];
    if (scale) x *= scale[k];
    _Float16 h = (_Float16)x;
    hi[p] = h;
    lo[p] = (_Float16)(x - (float)h);
}

__global__ __launch_bounds__(256) void k_packall(
    const float* __restrict__ W1, const float* __restrict__ W2,
    const float* __restrict__ Wm, const float* __restrict__ Wv,
    const float* __restrict__ CB, const float* __restrict__ ln_g,
    const float* __restrict__ ln_b, const float* __restrict__ b2,
    _Float16* __restrict__ W1h, _Float16* __restrict__ W1l,
    _Float16* __restrict__ W2h, _Float16* __restrict__ W2l,
    _Float16* __restrict__ Wmh, _Float16* __restrict__ Wml,
    _Float16* __restrict__ Wvh, _Float16* __restrict__ Wvl,
    _Float16* __restrict__ CBh, _Float16* __restrict__ CBl,
    float* __restrict__ cn, float* __restrict__ v0, float* __restrict__ v1,
    float* __restrict__ losss)
{
    const int bi = blockIdx.x;
    const int tid = threadIdx.x;
    if (bi == 0 && tid == 0) *losss = 0.f;

    if (bi < 1024) {
        pack_body(W1, W1h, W1l, 3, HID, bi * 256 + tid, (const float*)0);
    } else if (bi < 2048) {
        pack_body(W2, W2h, W2l, 5, EMB, (bi - 1024) * 256 + tid, ln_g);
    } else if (bi < 2176) {
        pack_body(Wm, Wmh, Wml, 3, ACT, (bi - 2048) * 256 + tid, (const float*)0);
    } else if (bi < 2304) {
        pack_body(Wv, Wvh, Wvl, 3, ACT, (bi - 2176) * 256 + tid, (const float*)0);
    } else if (bi < 2816) {
        int p = (bi - 2304) * 256 + tid;
        int j = p & 7;
        int l = (p >> 3) & 63;
        int q = p >> 9;
        int s = q & 7;
        int t = q >> 3;
        int n = t * 32 + (l & 31);
        int k = s * 16 + ((l >> 5) << 3) + j;
        float x = CB[(size_t)n * ACT + k];
        _Float16 h = (_Float16)x;
        CBh[p] = h;
        CBl[p] = (_Float16)(x - (float)h);
    } else if (bi < 2820) {
        int c = (bi - 2816) * 256 + tid;
        float s = 0.f;
        #pragma unroll
        for (int k = 0; k < ACT; k += 4) {
            float4 v = *(const float4*)&CB[(size_t)c * ACT + k];
            s += v.x*v.x + v.y*v.y + v.z*v.z + v.w*v.w;
        }
        cn[c] = s;
    } else {
        int n = tid;
        float a0 = 0.f, a1 = 0.f;
        for (int c = 0; c < HID; ++c) {
            float w2 = W2[(size_t)c * EMB + n];
            a1 = fmaf(ln_g[c], w2, a1);
            a0 = fmaf(ln_b[c], w2, a0);
        }
        v1[n] = a1;
        v0[n] = a0 + b2[n];
    }
}

// ---------------- K1: GEMM1 — 1024 threads, 256-row blocks, 16 waves x 16 rows
// grid: (RC/256) row-groups x 16 col-panels
__global__ __launch_bounds__(1024, 4) void k_gemm1(
    const float* __restrict__ X, const float* __restrict__ b1,
    const _Float16* __restrict__ W1h, const _Float16* __restrict__ W1l,
    _Float16* __restrict__ GHh, _Float16* __restrict__ GHl,
    float* __restrict__ stats, int row0)
{
    __shared__ _Float16 sh[32768];   // W panel hi [0,16384) lo [16384,32768); then h-bounce

    const int tid = threadIdx.x;
    const int w = tid >> 6, l = tid & 63, lr = l & 15, lg = l >> 4;
    const int p = blockIdx.x & 15;
    const int rg = blockIdx.x >> 4;
    const int rowc = rg * 256;

    // stage W panel (64 KB)
    {
        const float4* s0 = (const float4*)(W1h + (size_t)p * 16384);
        const float4* s1 = (const float4*)(W1l + (size_t)p * 16384);
        float4* d = (float4*)sh;
        #pragma unroll
        for (int i = 0; i < 2; ++i) {
            d[tid + 1024 * i] = s0[tid + 1024 * i];
            d[2048 + tid + 1024 * i] = s1[tid + 1024 * i];
        }
    }

    // A fragments: 16 rows per wave (same shape as R9)
    f16x8 a0[8], a1[8];
    {
        const float* xrow = X + (size_t)(row0 + rowc + w * 16 + lr) * SLOT + lg * 8;
        #pragma unroll
        for (int s = 0; s < 8; ++s) {
            float4 xa = *(const float4*)(xrow + 32 * s);
            float4 xb = *(const float4*)(xrow + 32 * s + 4);
            float xv[8] = {xa.x, xa.y, xa.z, xa.w, xb.x, xb.y, xb.z, xb.w};
            #pragma unroll
            for (int e = 0; e < 8; ++e) {
                _Float16 h = (_Float16)xv[e];
                a0[s][e] = h;
                a1[s][e] = (_Float16)(xv[e] - (float)h);
            }
        }
    }
    __syncthreads();

    f32x4 acc[4];
    #pragma unroll
    for (int t = 0; t < 4; ++t) acc[t] = (f32x4){0.f, 0.f, 0.f, 0.f};

    #pragma unroll
    for (int s = 0; s < 8; ++s) {
        #pragma unroll
        for (int t = 0; t < 4; ++t) {
            f16x8 bh = *(const f16x8*)&sh[((t * 8 + s) * 64 + l) * 8];
            f16x8 bl = *(const f16x8*)&sh[16384 + ((t * 8 + s) * 64 + l) * 8];
            acc[t] = __builtin_amdgcn_mfma_f32_16x16x32_f16(a0[s], bh, acc[t], 0, 0, 0);
            acc[t] = __builtin_amdgcn_mfma_f32_16x16x32_f16(a0[s], bl, acc[t], 0, 0, 0);
            acc[t] = __builtin_amdgcn_mfma_f32_16x16x32_f16(a1[s], bh, acc[t], 0, 0, 0);
        }
    }

    #pragma unroll
    for (int t = 0; t < 4; ++t) {
        float bb = b1[p * 64 + t * 16 + lr];
        #pragma unroll
        for (int r = 0; r < 4; ++r) acc[t][r] = fmaxf(acc[t][r] + bb, 0.f);
    }

    {
        float sum[4] = {0,0,0,0}, sq[4] = {0,0,0,0};
        #pragma unroll
        for (int t = 0; t < 4; ++t)
            #pragma unroll
            for (int r = 0; r < 4; ++r) {
                float v = acc[t][r];
                sum[r] += v; sq[r] = fmaf(v, v, sq[r]);
            }
        #pragma unroll
        for (int off = 1; off < 16; off <<= 1)
            #pragma unroll
            for (int r = 0; r < 4; ++r) {
                sum[r] += __shfl_xor(sum[r], off, 64);
                sq[r]  += __shfl_xor(sq[r],  off, 64);
            }
        if (lr == 0) {
            #pragma unroll
            for (int r = 0; r < 4; ++r) {
                size_t grow = (size_t)row0 + rowc + w * 16 + lg * 4 + r;
                float2 st = {sum[r], sq[r]};
                *(float2*)&stats[((size_t)p * R_ROWS + grow) * 2] = st;
            }
        }
    }
    __syncthreads();   // W panel reads done

    // bounce raw h (hi/lo) into LDS swizzled: 256 rows x 64 cols fits exactly
    #pragma unroll
    for (int t = 0; t < 4; ++t) {
        #pragma unroll
        for (int r = 0; r < 4; ++r) {
            int rowloc = w * 16 + lg * 4 + r;
            int col = t * 16 + lr;
            int cc = col >> 3, j = col & 7;
            int ad = rowloc * 64 + ((cc ^ (rowloc & 7)) << 3) + j;
            float v = acc[t][r];
            _Float16 h = (_Float16)v;
            sh[ad] = h;
            sh[16384 + ad] = (_Float16)(v - (float)h);
        }
    }
    __syncthreads();

    // fragment-linear store: 2048 f16x8 units per array
    #pragma unroll
    for (int i = 0; i < 2; ++i) {
        int u = tid + 1024 * i;              // 0..2047
        int RTl = u >> 7;                    // 0..15
        int Sl  = (u >> 6) & 1;
        int li  = u & 63;
        int row = RTl * 16 + (li & 15);
        int cc  = Sl * 4 + (li >> 4);
        int ad  = row * 64 + ((cc ^ (row & 7)) << 3);
        f16x8 vh = *(const f16x8*)&sh[ad];
        f16x8 vl = *(const f16x8*)&sh[16384 + ad];
        size_t RTg = (size_t)rg * 16 + RTl;
        size_t off = ((RTg * 32 + (2 * p + Sl)) * 64 + li) * 8;
        *(f16x8*)&GHh[off] = vh;
        *(f16x8*)&GHl[off] = vl;
    }
}

// ---------------- K2: GEMM2 (raw H @ W2g) + LN-fold + heads (R9 exact) --------
__global__ __launch_bounds__(512, 4) void k_gemm2(
    const _Float16* __restrict__ GHh, const _Float16* __restrict__ GHl,
    const _Float16* __restrict__ W2h, const _Float16* __restrict__ W2l,
    const _Float16* __restrict__ Wmh, const _Float16* __restrict__ Wml,
    const _Float16* __restrict__ Wvh, const _Float16* __restrict__ Wvl,
    const float* __restrict__ stats, const float* __restrict__ v0,
    const float* __restrict__ v1, const float* __restrict__ bm,
    const float* __restrict__ bv,
    float* __restrict__ MT, float* __restrict__ VT, int row0)
{
    __shared__ _Float16 sh[32768];
    __shared__ float mu_s[64], rs_s[64];

    const int tid = threadIdx.x;
    const int w = tid >> 6, l = tid & 63, lr = l & 15, lg = l >> 4;
    const int rb = blockIdx.x;
    const size_t grow0 = (size_t)row0 + rb * 64;

    if (tid < 64) {
        float s = 0.f, q = 0.f;
        #pragma unroll
        for (int pp = 0; pp < 16; ++pp) {
            float2 st = *(const float2*)&stats[((size_t)pp * R_ROWS + grow0 + tid) * 2];
            s += st.x; q += st.y;
        }
        float mu = s * (1.f / HID);
        float var = q * (1.f / HID) - mu * mu;
        mu_s[tid] = mu;
        rs_s[tid] = 1.f / sqrtf(var + 1e-5f);
    }

    float v0r[2], v1r[2];
    #pragma unroll
    for (int t = 0; t < 2; ++t) {
        int n = w * 32 + t * 16 + lr;
        v0r[t] = v0[n];
        v1r[t] = v1[n];
    }

    f32x4 acc[4][2];
    #pragma unroll
    for (int rt = 0; rt < 4; ++rt)
        #pragma unroll
        for (int t = 0; t < 2; ++t) acc[rt][t] = (f32x4){0.f, 0.f, 0.f, 0.f};

    for (int kp = 0; kp < 8; ++kp) {
        __syncthreads();
        #pragma unroll
        for (int i = 0; i < 4; ++i) {
            int u = tid + 512 * i;
            int arr = u >> 10;
            int ui = u & 1023;
            int RTl = ui >> 8;
            int rem = ui & 255;
            size_t gu = ((size_t)(rb * 4 + RTl) * 32 + kp * 4) * 64 + rem;
            const _Float16* src = arr ? GHl : GHh;
            *(f16x8*)&sh[(size_t)arr * 8192 + (size_t)ui * 8] = *(const f16x8*)&src[gu * 8];
        }
        __syncthreads();

        #pragma unroll
        for (int sl = 0; sl < 4; ++sl) {
            f16x8 bh[2], bl[2];
            #pragma unroll
            for (int t = 0; t < 2; ++t) {
                int tg = w * 2 + t;
                size_t o = ((size_t)(tg * 32 + kp * 4 + sl) * 64 + l) * 8;
                bh[t] = *(const f16x8*)&W2h[o];
                bl[t] = *(const f16x8*)&W2l[o];
            }
            #pragma unroll
            for (int rt = 0; rt < 4; ++rt) {
                f16x8 ah = *(const f16x8*)&sh[((rt * 4 + sl) * 64 + l) * 8];
                f16x8 al = *(const f16x8*)&sh[8192 + ((rt * 4 + sl) * 64 + l) * 8];
                #pragma unroll
                for (int t = 0; t < 2; ++t) {
                    acc[rt][t] = __builtin_amdgcn_mfma_f32_16x16x32_f16(ah, bh[t], acc[rt][t], 0, 0, 0);
                    acc[rt][t] = __builtin_amdgcn_mfma_f32_16x16x32_f16(ah, bl[t], acc[rt][t], 0, 0, 0);
                    acc[rt][t] = __builtin_amdgcn_mfma_f32_16x16x32_f16(al, bh[t], acc[rt][t], 0, 0, 0);
                }
            }
        }
    }
    __syncthreads();

    #pragma unroll
    for (int rt = 0; rt < 4; ++rt) {
        #pragma unroll
        for (int t = 0; t < 2; ++t) {
            int n = w * 32 + t * 16 + lr;
            int cc = n >> 3, j = n & 7;
            #pragma unroll
            for (int r = 0; r < 4; ++r) {
                int row = rt * 16 + lg * 4 + r;
                float mu = mu_s[row], rs = rs_s[row];
                float e = rs * acc[rt][t][r] - rs * mu * v1r[t] + v0r[t];
                _Float16 h = (_Float16)e;
                int ad = row * 256 + ((cc ^ (row & 7)) << 3) + j;
                sh[ad] = h;
                sh[16384 + ad] = (_Float16)(e - (float)h);
            }
        }
    }
    __syncthreads();

    const _Float16* WXh = (w < 4) ? Wmh : Wvh;
    const _Float16* WXl = (w < 4) ? Wml : Wvl;
    f32x4 acc3[4][2];
    #pragma unroll
    for (int rt = 0; rt < 4; ++rt)
        #pragma unroll
        for (int t = 0; t < 2; ++t) acc3[rt][t] = (f32x4){0.f, 0.f, 0.f, 0.f};

    #pragma unroll
    for (int s = 0; s < 8; ++s) {
        f16x8 bh[2], bl[2];
        #pragma unroll
        for (int t = 0; t < 2; ++t) {
            int tg = (w & 3) * 2 + t;
            size_t o = ((size_t)(tg * 8 + s) * 64 + l) * 8;
            bh[t] = *(const f16x8*)&WXh[o];
            bl[t] = *(const f16x8*)&WXl[o];
        }
        #pragma unroll
        for (int rt = 0; rt < 4; ++rt) {
            int row = rt * 16 + lr;
            int cc = s * 4 + lg;
            int ad = row * 256 + ((cc ^ (row & 7)) << 3);
            f16x8 ah = *(const f16x8*)&sh[ad];
            f16x8 al = *(const f16x8*)&sh[16384 + ad];
            #pragma unroll
            for (int t = 0; t < 2; ++t) {
                acc3[rt][t] = __builtin_amdgcn_mfma_f32_16x16x32_f16(ah, bh[t], acc3[rt][t], 0, 0, 0);
                acc3[rt][t] = __builtin_amdgcn_mfma_f32_16x16x32_f16(ah, bl[t], acc3[rt][t], 0, 0, 0);
                acc3[rt][t] = __builtin_amdgcn_mfma_f32_16x16x32_f16(al, bh[t], acc3[rt][t], 0, 0, 0);
            }
        }
    }

    #pragma unroll
    for (int rt = 0; rt < 4; ++rt) {
        #pragma unroll
        for (int t = 0; t < 2; ++t) {
            int a = (w & 3) * 32 + t * 16 + lr;
            float bx = (w < 4) ? bm[a] : bv[a];
            #pragma unroll
            for (int r = 0; r < 4; ++r) {
                size_t grow = grow0 + rt * 16 + lg * 4 + r;
                float vv = acc3[rt][t][r] + bx;
                if (w < 4) MT[grow * ACT + a] = vv;
                else       VT[grow * ACT + a] = fabsf(vv);
            }
        }
    }
}

// ---------------- fused action + VQ + finalize (R9, launch_bounds 4) ----------
__global__ __launch_bounds__(256, 4) void k_vq32(
    const float* __restrict__ MT, const float* __restrict__ VT,
    const float* __restrict__ noise,
    const _Float16* __restrict__ CBh, const _Float16* __restrict__ CBl,
    const float* __restrict__ cn, const float* __restrict__ CB,
    float* __restrict__ out, float* __restrict__ losss)
{
    typedef float f32x16 __attribute__((ext_vector_type(16)));
    __shared__ _Float16 Zh[32 * 128];
    __shared__ _Float16 Zl[32 * 128];
    __shared__ float pb[4][32];
    __shared__ int   pi[4][32];
    __shared__ int   idx_s[32];
    __shared__ float red[4];

    const int tid = threadIdx.x;
    const int rowbase = blockIdx.x * 32;
    const int a = tid & 127;
    const int rhalf = tid >> 7;
    const int ga = a >> 3, ja = a & 7;

    for (int g = 0; g < 2; ++g) {
        float m1v[8], m2v[8], v1v[8], v2v[8], nzv[8];
        #pragma unroll
        for (int i = 0; i < 8; ++i) {
            int row = g * 16 + 2 * i + rhalf;
            int m = rowbase + row;
            int b = m / 372;
            int r1 = m + 12 * b;
            int r2 = r1 + 12;
            m1v[i] = MT[(size_t)r1 * ACT + a];
            m2v[i] = MT[(size_t)r2 * ACT + a];
            v1v[i] = VT[(size_t)r1 * ACT + a];
            v2v[i] = VT[(size_t)r2 * ACT + a];
            nzv[i] = noise[(size_t)m * ACT + a];
        }
        #pragma unroll
        for (int i = 0; i < 8; ++i) {
            int row = g * 16 + 2 * i + rhalf;
            int m = rowbase + row;
            float adm = m2v[i] - m1v[i];
            float adv = v2v[i] + v1v[i];
            float z = nzv[i] * sqrtf(adv + 1e-6f) + adm;
            int np = m / 12, s = m - np * 12;
            out[OFF_AD + (size_t)(np * 24 + s) * ACT + a] = adm;
            out[OFF_AD + (size_t)(np * 24 + 12 + s) * ACT + a] = adv;
            out[OFF_Z + (size_t)m * ACT + a] = z;
            _Float16 h = (_Float16)z;
            int ad = row * 128 + (((ga ^ (row & 15))) << 3) + ja;
            Zh[ad] = h;
            Zl[ad] = (_Float16)(z - (float)h);
        }
    }
    __syncthreads();

    const int w = tid >> 6, l = tid & 63;
    const int col = l & 31, hw = l >> 5;

    float best[16];
    int bidx[16];
    #pragma unroll
    for (int r = 0; r < 16; ++r) { best[r] = 3.4e38f; bidx[r] = 0; }

    for (int cc2 = 0; cc2 < 2; ++cc2) {
        f32x16 acc[4];
        #pragma unroll
        for (int t = 0; t < 4; ++t)
            #pragma unroll
            for (int r = 0; r < 16; ++r) acc[t][r] = 0.f;

        #pragma unroll
        for (int s = 0; s < 8; ++s) {
            int ad = col * 128 + (((s * 2 + hw) ^ (col & 15)) << 3);
            f16x8 ah = *(const f16x8*)&Zh[ad];
            f16x8 al = *(const f16x8*)&Zl[ad];
            #pragma unroll
            for (int t = 0; t < 4; ++t) {
                int tg = w * 8 + cc2 * 4 + t;
                f16x8 bh = *(const f16x8*)(CBh + ((size_t)(tg * 8 + s) * 64 + l) * 8);
                f16x8 bl = *(const f16x8*)(CBl + ((size_t)(tg * 8 + s) * 64 + l) * 8);
                acc[t] = __builtin_amdgcn_mfma_f32_32x32x16_f16(ah, bh, acc[t], 0, 0, 0);
                acc[t] = __builtin_amdgcn_mfma_f32_32x32x16_f16(ah, bl, acc[t], 0, 0, 0);
                acc[t] = __builtin_amdgcn_mfma_f32_32x32x16_f16(al, bh, acc[t], 0, 0, 0);
            }
        }

        float cnv[4];
        #pragma unroll
        for (int t = 0; t < 4; ++t) cnv[t] = cn[(w * 8 + cc2 * 4 + t) * 32 + col];

        #pragma unroll
        for (int reg = 0; reg < 16; ++reg) {
            #pragma unroll
            for (int t = 0; t < 4; ++t) {
                float d = cnv[t] - 2.f * acc[t][reg];
                int gi = (w * 8 + cc2 * 4 + t) * 32 + col;
                if (d < best[reg]) { best[reg] = d; bidx[reg] = gi; }
            }
        }
    }

    #pragma unroll
    for (int reg = 0; reg < 16; ++reg) {
        float bv_ = best[reg];
        int bi_ = bidx[reg];
        #pragma unroll
        for (int off = 1; off < 32; off <<= 1) {
            float ov = __shfl_xor(bv_, off, 64);
            int   oi = __shfl_xor(bi_, off, 64);
            if (ov < bv_ || (ov == bv_ && oi < bi_)) { bv_ = ov; bi_ = oi; }
        }
        if (col == 0) {
            int mrow = (reg & 3) + 8 * (reg >> 2) + 4 * hw;
            pb[w][mrow] = bv_;
            pi[w][mrow] = bi_;
        }
    }
    __syncthreads();

    if (tid < 32) {
        float bb = pb[0][tid];
        int bi_ = pi[0][tid];
        #pragma unroll
        for (int w2 = 1; w2 < 4; ++w2) {
            float v = pb[w2][tid];
            int ii = pi[w2][tid];
            if (v < bb || (v == bb && ii < bi_)) { bb = v; bi_ = ii; }
        }
        idx_s[tid] = bi_;
        out[OFF_IDX + rowbase + tid] = (float)bi_;
    }
    __syncthreads();

    float ls = 0.f;
    for (int g = 0; g < 2; ++g) {
        int civ[8]; float zv[8], qv[8];
        #pragma unroll
        for (int i = 0; i < 8; ++i) {
            int row = g * 16 + 2 * i + rhalf;
            civ[i] = idx_s[row];
            int ad = row * 128 + (((ga ^ (row & 15))) << 3) + ja;
            zv[i] = (float)Zh[ad] + (float)Zl[ad];
        }
        #pragma unroll
        for (int i = 0; i < 8; ++i) qv[i] = CB[(size_t)civ[i] * ACT + a];
        #pragma unroll
        for (int i = 0; i < 8; ++i) {
            int row = g * 16 + 2 * i + rhalf;
            size_t m = (size_t)(rowbase + row);
            float diff = zv[i] - qv[i];
            out[OFF_QS + m * ACT + a] = zv[i] + (qv[i] - zv[i]);
            out[OFF_AV + m * ACT + a] = diff;
            ls = fmaf(diff, diff, ls);
        }
    }
    #pragma unroll
    for (int off = 32; off; off >>= 1) ls += __shfl_xor(ls, off, 64);
    if (l == 0) red[w] = ls;
    __syncthreads();
    if (tid == 0) atomicAdd(losss, red[0] + red[1] + red[2] + red[3]);
}

__global__ void k_losses(const float* __restrict__ losss, float* __restrict__ out)
{
    float v = *losss * (1.f / 6094848.f);
    out[OFF_QL] = v;
    out[OFF_CL] = v;
}

extern "C" void kernel_launch(void* const* d_in, const int* in_sizes, int n_in,
                              void* d_out, int out_size, void* d_ws, size_t ws_size,
                              hipStream_t stream)
{
    const float* slots = (const float*)d_in[0];
    const float* noise = (const float*)d_in[1];
    const float* W1    = (const float*)d_in[2];
    const float* b1    = (const float*)d_in[3];
    const float* ln_g  = (const float*)d_in[4];
    const float* ln_b  = (const float*)d_in[5];
    const float* W2    = (const float*)d_in[6];
    const float* b2    = (const float*)d_in[7];
    const float* Wm    = (const float*)d_in[8];
    const float* bm    = (const float*)d_in[9];
    const float* Wv    = (const float*)d_in[10];
    const float* bv    = (const float*)d_in[11];
    const float* CB    = (const float*)d_in[12];
    float* out = (float*)d_out;
    float* ws  = (float*)d_ws;

    size_t ws_floats = ws_size / 4;
    int nchunk = (ws_floats >= 41000000) ? 2 : 4;
    int RC = R_ROWS / nchunk;

    _Float16* GHh = (_Float16*)ws;
    _Float16* GHl = (_Float16*)(ws + (size_t)RC * 512);
    float* MT = ws + (size_t)RC * 1024;
    float* VT = MT + 6291456;
    float* wb = VT + 6291456;
    _Float16* W1h = (_Float16*)(wb + 0);
    _Float16* W1l = (_Float16*)(wb + 131072);
    _Float16* W2h = (_Float16*)(wb + 262144);
    _Float16* W2l = (_Float16*)(wb + 393216);
    _Float16* Wmh = (_Float16*)(wb + 524288);
    _Float16* Wml = (_Float16*)(wb + 540672);
    _Float16* Wvh = (_Float16*)(wb + 557056);
    _Float16* Wvl = (_Float16*)(wb + 573440);
    _Float16* CBh = (_Float16*)(wb + 589824);
    _Float16* CBl = (_Float16*)(wb + 655360);
    float* cn    = wb + 720896;
    float* v0    = wb + 721920;
    float* v1    = wb + 722176;
    float* losss = wb + 722432;
    float* stats = wb + 722688;

    hipLaunchKernelGGL(k_packall, dim3(2821), dim3(256), 0, stream,
                       W1, W2, Wm, Wv, CB, ln_g, ln_b, b2,
                       W1h, W1l, W2h, W2l, Wmh, Wml, Wvh, Wvl, CBh, CBl,
                       cn, v0, v1, losss);

    for (int c = 0; c < nchunk; ++c) {
        int row0 = c * RC;
        hipLaunchKernelGGL(k_gemm1, dim3((RC / 256) * 16), dim3(1024), 0, stream,
                           slots, b1, W1h, W1l, GHh, GHl, stats, row0);
        hipLaunchKernelGGL(k_gemm2, dim3(RC / 64), dim3(512), 0, stream,
                           GHh, GHl, W2h, W2l, Wmh, Wml, Wvh, Wvl,
                           stats, v0, v1, bm, bv, MT, VT, row0);
    }

    hipLaunchKernelGGL(k_vq32, dim3(M_ROWS / 32), dim3(256), 0, stream,
                       MT, VT, noise, CBh, CBl, cn, CB, out, losss);
    hipLaunchKernelGGL(k_losses, dim3(1), dim3(1), 0, stream, losss, out);
}

// Round 12
// 506.884 us; speedup vs baseline: 1.0998x; 1.0433x over previous
//
#include <hip/hip_runtime.h>
#include <math.h>

#define HID 1024
#define SLOT 256
#define EMB 256
#define ACT 128
#define NCODE 1024
#define R_ROWS 49152
#define M_ROWS 47616
#define NCHUNK 3
#define RC 16384

// output offsets (float elements)
#define OFF_AD 0
#define OFF_Z  12189696
#define OFF_AV 18284544
#define OFF_QS 24379392
#define OFF_IDX 30474240
#define OFF_QL 30521856
#define OFF_CL 30521857

typedef _Float16 f16x8 __attribute__((ext_vector_type(8)));
typedef float f32x4 __attribute__((ext_vector_type(4)));

// ---------------- fused pack kernel ----------------
__device__ __forceinline__ void pack_body(
    const float* __restrict__ W, _Float16* __restrict__ hi, _Float16* __restrict__ lo,
    int lgS, int N, int p, const float* __restrict__ scale)
{
    int j = p & 7;
    int l = (p >> 3) & 63;
    int q = p >> 9;
    int s = q & ((1 << lgS) - 1);
    int t = q >> lgS;
    int n = t * 16 + (l & 15);
    int k = s * 32 + ((l >> 4) << 3) + j;
    float x = W[(size_t)k * N + n];
    if (scale) x *= scale[k];
    _Float16 h = (_Float16)x;
    hi[p] = h;
    lo[p] = (_Float16)(x - (float)h);
}

__global__ __launch_bounds__(256) void k_packall(
    const float* __restrict__ W1, const float* __restrict__ W2,
    const float* __restrict__ Wm, const float* __restrict__ Wv,
    const float* __restrict__ CB, const float* __restrict__ ln_g,
    const float* __restrict__ ln_b, const float* __restrict__ b2,
    _Float16* __restrict__ W1h, _Float16* __restrict__ W1l,
    _Float16* __restrict__ W2h, _Float16* __restrict__ W2l,
    _Float16* __restrict__ Wmh, _Float16* __restrict__ Wml,
    _Float16* __restrict__ Wvh, _Float16* __restrict__ Wvl,
    _Float16* __restrict__ CBh, _Float16* __restrict__ CBl,
    float* __restrict__ cn, float* __restrict__ v0, float* __restrict__ v1,
    float* __restrict__ losss)
{
    const int bi = blockIdx.x;
    const int tid = threadIdx.x;
    if (bi == 0 && tid == 0) *losss = 0.f;

    if (bi < 1024) {
        pack_body(W1, W1h, W1l, 3, HID, bi * 256 + tid, (const float*)0);
    } else if (bi < 2048) {
        pack_body(W2, W2h, W2l, 5, EMB, (bi - 1024) * 256 + tid, ln_g);
    } else if (bi < 2176) {
        pack_body(Wm, Wmh, Wml, 3, ACT, (bi - 2048) * 256 + tid, (const float*)0);
    } else if (bi < 2304) {
        pack_body(Wv, Wvh, Wvl, 3, ACT, (bi - 2176) * 256 + tid, (const float*)0);
    } else if (bi < 2816) {
        int p = (bi - 2304) * 256 + tid;
        int j = p & 7;
        int l = (p >> 3) & 63;
        int q = p >> 9;
        int s = q & 7;
        int t = q >> 3;
        int n = t * 32 + (l & 31);
        int k = s * 16 + ((l >> 5) << 3) + j;
        float x = CB[(size_t)n * ACT + k];
        _Float16 h = (_Float16)x;
        CBh[p] = h;
        CBl[p] = (_Float16)(x - (float)h);
    } else if (bi < 2820) {
        int c = (bi - 2816) * 256 + tid;
        float s = 0.f;
        #pragma unroll
        for (int k = 0; k < ACT; k += 4) {
            float4 v = *(const float4*)&CB[(size_t)c * ACT + k];
            s += v.x*v.x + v.y*v.y + v.z*v.z + v.w*v.w;
        }
        cn[c] = s;
    } else {
        int n = tid;
        float a0 = 0.f, a1 = 0.f;
        for (int c = 0; c < HID; ++c) {
            float w2 = W2[(size_t)c * EMB + n];
            a1 = fmaf(ln_g[c], w2, a1);
            a0 = fmaf(ln_b[c], w2, a0);
        }
        v1[n] = a1;
        v0[n] = a0 + b2[n];
    }
}

// ---------------- K1: GEMM1 — 1024 threads, 256-row blocks ----------------
// grid: (RC/256) row-groups x 16 col-panels
__global__ __launch_bounds__(1024, 4) void k_gemm1(
    const float* __restrict__ X, const float* __restrict__ b1,
    const _Float16* __restrict__ W1h, const _Float16* __restrict__ W1l,
    _Float16* __restrict__ GHh, _Float16* __restrict__ GHl,
    float* __restrict__ stats, int row0)
{
    __shared__ _Float16 sh[32768];   // W panel hi [0,16384) lo [16384,32768); then h-bounce

    const int tid = threadIdx.x;
    const int w = tid >> 6, l = tid & 63, lr = l & 15, lg = l >> 4;
    const int p = blockIdx.x & 15;
    const int rg = blockIdx.x >> 4;
    const int rowc = rg * 256;

    {
        const float4* s0 = (const float4*)(W1h + (size_t)p * 16384);
        const float4* s1 = (const float4*)(W1l + (size_t)p * 16384);
        float4* d = (float4*)sh;
        #pragma unroll
        for (int i = 0; i < 2; ++i) {
            d[tid + 1024 * i] = s0[tid + 1024 * i];
            d[2048 + tid + 1024 * i] = s1[tid + 1024 * i];
        }
    }

    f16x8 a0[8], a1[8];
    {
        const float* xrow = X + (size_t)(row0 + rowc + w * 16 + lr) * SLOT + lg * 8;
        #pragma unroll
        for (int s = 0; s < 8; ++s) {
            float4 xa = *(const float4*)(xrow + 32 * s);
            float4 xb = *(const float4*)(xrow + 32 * s + 4);
            float xv[8] = {xa.x, xa.y, xa.z, xa.w, xb.x, xb.y, xb.z, xb.w};
            #pragma unroll
            for (int e = 0; e < 8; ++e) {
                _Float16 h = (_Float16)xv[e];
                a0[s][e] = h;
                a1[s][e] = (_Float16)(xv[e] - (float)h);
            }
        }
    }
    __syncthreads();

    f32x4 acc[4];
    #pragma unroll
    for (int t = 0; t < 4; ++t) acc[t] = (f32x4){0.f, 0.f, 0.f, 0.f};

    #pragma unroll
    for (int s = 0; s < 8; ++s) {
        #pragma unroll
        for (int t = 0; t < 4; ++t) {
            f16x8 bh = *(const f16x8*)&sh[((t * 8 + s) * 64 + l) * 8];
            f16x8 bl = *(const f16x8*)&sh[16384 + ((t * 8 + s) * 64 + l) * 8];
            acc[t] = __builtin_amdgcn_mfma_f32_16x16x32_f16(a0[s], bh, acc[t], 0, 0, 0);
            acc[t] = __builtin_amdgcn_mfma_f32_16x16x32_f16(a0[s], bl, acc[t], 0, 0, 0);
            acc[t] = __builtin_amdgcn_mfma_f32_16x16x32_f16(a1[s], bh, acc[t], 0, 0, 0);
        }
    }

    #pragma unroll
    for (int t = 0; t < 4; ++t) {
        float bb = b1[p * 64 + t * 16 + lr];
        #pragma unroll
        for (int r = 0; r < 4; ++r) acc[t][r] = fmaxf(acc[t][r] + bb, 0.f);
    }

    {
        float sum[4] = {0,0,0,0}, sq[4] = {0,0,0,0};
        #pragma unroll
        for (int t = 0; t < 4; ++t)
            #pragma unroll
            for (int r = 0; r < 4; ++r) {
                float v = acc[t][r];
                sum[r] += v; sq[r] = fmaf(v, v, sq[r]);
            }
        #pragma unroll
        for (int off = 1; off < 16; off <<= 1)
            #pragma unroll
            for (int r = 0; r < 4; ++r) {
                sum[r] += __shfl_xor(sum[r], off, 64);
                sq[r]  += __shfl_xor(sq[r],  off, 64);
            }
        if (lr == 0) {
            #pragma unroll
            for (int r = 0; r < 4; ++r) {
                size_t grow = (size_t)row0 + rowc + w * 16 + lg * 4 + r;
                float2 st = {sum[r], sq[r]};
                *(float2*)&stats[((size_t)p * R_ROWS + grow) * 2] = st;
            }
        }
    }
    __syncthreads();

    #pragma unroll
    for (int t = 0; t < 4; ++t) {
        #pragma unroll
        for (int r = 0; r < 4; ++r) {
            int rowloc = w * 16 + lg * 4 + r;
            int col = t * 16 + lr;
            int cc = col >> 3, j = col & 7;
            int ad = rowloc * 64 + ((cc ^ (rowloc & 7)) << 3) + j;
            float v = acc[t][r];
            _Float16 h = (_Float16)v;
            sh[ad] = h;
            sh[16384 + ad] = (_Float16)(v - (float)h);
        }
    }
    __syncthreads();

    #pragma unroll
    for (int i = 0; i < 2; ++i) {
        int u = tid + 1024 * i;              // 0..2047
        int RTl = u >> 7;                    // 0..15
        int Sl  = (u >> 6) & 1;
        int li  = u & 63;
        int row = RTl * 16 + (li & 15);
        int cc  = Sl * 4 + (li >> 4);
        int ad  = row * 64 + ((cc ^ (row & 7)) << 3);
        f16x8 vh = *(const f16x8*)&sh[ad];
        f16x8 vl = *(const f16x8*)&sh[16384 + ad];
        size_t RTg = (size_t)rg * 16 + RTl;
        size_t off = ((RTg * 32 + (2 * p + Sl)) * 64 + li) * 8;
        *(f16x8*)&GHh[off] = vh;
        *(f16x8*)&GHl[off] = vl;
    }
}

// ---------------- K2: GEMM2 + LN-fold + heads — 32-row blocks ----------------
// grid: RC/32; waves split e-cols (32 each), RT loop covers 2 row-tiles
__global__ __launch_bounds__(512, 4) void k_gemm2(
    const _Float16* __restrict__ GHh, const _Float16* __restrict__ GHl,
    const _Float16* __restrict__ W2h, const _Float16* __restrict__ W2l,
    const _Float16* __restrict__ Wmh, const _Float16* __restrict__ Wml,
    const _Float16* __restrict__ Wvh, const _Float16* __restrict__ Wvl,
    const float* __restrict__ stats, const float* __restrict__ v0,
    const float* __restrict__ v1, const float* __restrict__ bm,
    const float* __restrict__ bv,
    float* __restrict__ MT, float* __restrict__ VT, int row0)
{
    __shared__ _Float16 sh[32768];   // kp stage: hi [0,4096) lo [4096,8192); E tile: hi [0,8192) lo [8192,16384)
    __shared__ float mu_s[32], rs_s[32];

    const int tid = threadIdx.x;
    const int w = tid >> 6, l = tid & 63, lr = l & 15, lg = l >> 4;
    const int rb = blockIdx.x;
    const size_t grow0 = (size_t)row0 + rb * 32;

    if (tid < 32) {
        float s = 0.f, q = 0.f;
        #pragma unroll
        for (int pp = 0; pp < 16; ++pp) {
            float2 st = *(const float2*)&stats[((size_t)pp * R_ROWS + grow0 + tid) * 2];
            s += st.x; q += st.y;
        }
        float mu = s * (1.f / HID);
        float var = q * (1.f / HID) - mu * mu;
        mu_s[tid] = mu;
        rs_s[tid] = 1.f / sqrtf(var + 1e-5f);
    }

    float v0r[2], v1r[2];
    #pragma unroll
    for (int t = 0; t < 2; ++t) {
        int n = w * 32 + t * 16 + lr;
        v0r[t] = v0[n];
        v1r[t] = v1[n];
    }

    f32x4 acc[2][2];
    #pragma unroll
    for (int rt = 0; rt < 2; ++rt)
        #pragma unroll
        for (int t = 0; t < 2; ++t) acc[rt][t] = (f32x4){0.f, 0.f, 0.f, 0.f};

    for (int kp = 0; kp < 8; ++kp) {
        __syncthreads();   // previous stage consumed (also orders mu_s on first iter)
        // stage H k-panel: [2 RT][4 sl][64 l][8 j] hi+lo = 16 KB
        {
            int u = tid;                       // pass 1: u 0..511
            #pragma unroll
            for (int i = 0; i < 2; ++i) {
                int uu = u + 512 * i;          // 0..1023
                int arr = uu >> 9;
                int ui = uu & 511;
                int RTl = ui >> 8;
                int rem = ui & 255;
                size_t gu = ((size_t)(rb * 2 + RTl) * 32 + kp * 4) * 64 + rem;
                const _Float16* src = arr ? GHl : GHh;
                *(f16x8*)&sh[(size_t)arr * 4096 + (size_t)ui * 8] = *(const f16x8*)&src[gu * 8];
            }
        }
        __syncthreads();

        #pragma unroll
        for (int sl = 0; sl < 4; ++sl) {
            f16x8 bh[2], bl[2];
            #pragma unroll
            for (int t = 0; t < 2; ++t) {
                int tg = w * 2 + t;
                size_t o = ((size_t)(tg * 32 + kp * 4 + sl) * 64 + l) * 8;
                bh[t] = *(const f16x8*)&W2h[o];
                bl[t] = *(const f16x8*)&W2l[o];
            }
            #pragma unroll
            for (int rt = 0; rt < 2; ++rt) {
                f16x8 ah = *(const f16x8*)&sh[((rt * 4 + sl) * 64 + l) * 8];
                f16x8 al = *(const f16x8*)&sh[4096 + ((rt * 4 + sl) * 64 + l) * 8];
                #pragma unroll
                for (int t = 0; t < 2; ++t) {
                    acc[rt][t] = __builtin_amdgcn_mfma_f32_16x16x32_f16(ah, bh[t], acc[rt][t], 0, 0, 0);
                    acc[rt][t] = __builtin_amdgcn_mfma_f32_16x16x32_f16(ah, bl[t], acc[rt][t], 0, 0, 0);
                    acc[rt][t] = __builtin_amdgcn_mfma_f32_16x16x32_f16(al, bh[t], acc[rt][t], 0, 0, 0);
                }
            }
        }
    }
    __syncthreads();

    // E epilogue with LN-fold; E tile 32 rows x 256 cols, swizzled
    #pragma unroll
    for (int rt = 0; rt < 2; ++rt) {
        #pragma unroll
        for (int t = 0; t < 2; ++t) {
            int n = w * 32 + t * 16 + lr;
            int cc = n >> 3, j = n & 7;
            #pragma unroll
            for (int r = 0; r < 4; ++r) {
                int row = rt * 16 + lg * 4 + r;
                float mu = mu_s[row], rs = rs_s[row];
                float e = rs * acc[rt][t][r] - rs * mu * v1r[t] + v0r[t];
                _Float16 h = (_Float16)e;
                int ad = row * 256 + ((cc ^ (row & 7)) << 3) + j;
                sh[ad] = h;
                sh[8192 + ad] = (_Float16)(e - (float)h);
            }
        }
    }
    __syncthreads();

    // heads: waves 0..3 -> MT, 4..7 -> VT; 32 rows x 32 head-cols per wave
    const _Float16* WXh = (w < 4) ? Wmh : Wvh;
    const _Float16* WXl = (w < 4) ? Wml : Wvl;
    f32x4 acc3[2][2];
    #pragma unroll
    for (int rt = 0; rt < 2; ++rt)
        #pragma unroll
        for (int t = 0; t < 2; ++t) acc3[rt][t] = (f32x4){0.f, 0.f, 0.f, 0.f};

    #pragma unroll
    for (int s = 0; s < 8; ++s) {
        f16x8 bh[2], bl[2];
        #pragma unroll
        for (int t = 0; t < 2; ++t) {
            int tg = (w & 3) * 2 + t;
            size_t o = ((size_t)(tg * 8 + s) * 64 + l) * 8;
            bh[t] = *(const f16x8*)&WXh[o];
            bl[t] = *(const f16x8*)&WXl[o];
        }
        #pragma unroll
        for (int rt = 0; rt < 2; ++rt) {
            int row = rt * 16 + lr;
            int cc = s * 4 + lg;
            int ad = row * 256 + ((cc ^ (row & 7)) << 3);
            f16x8 ah = *(const f16x8*)&sh[ad];
            f16x8 al = *(const f16x8*)&sh[8192 + ad];
            #pragma unroll
            for (int t = 0; t < 2; ++t) {
                acc3[rt][t] = __builtin_amdgcn_mfma_f32_16x16x32_f16(ah, bh[t], acc3[rt][t], 0, 0, 0);
                acc3[rt][t] = __builtin_amdgcn_mfma_f32_16x16x32_f16(ah, bl[t], acc3[rt][t], 0, 0, 0);
                acc3[rt][t] = __builtin_amdgcn_mfma_f32_16x16x32_f16(al, bh[t], acc3[rt][t], 0, 0, 0);
            }
        }
    }

    #pragma unroll
    for (int rt = 0; rt < 2; ++rt) {
        #pragma unroll
        for (int t = 0; t < 2; ++t) {
            int a = (w & 3) * 32 + t * 16 + lr;
            float bx = (w < 4) ? bm[a] : bv[a];
            #pragma unroll
            for (int r = 0; r < 4; ++r) {
                size_t grow = grow0 + rt * 16 + lg * 4 + r;
                float vv = acc3[rt][t][r] + bx;
                if (w < 4) MT[grow * ACT + a] = vv;
                else       VT[grow * ACT + a] = fabsf(vv);
            }
        }
    }
}

// ---------------- fused action + VQ + finalize (R9 exact, (256,3)) ------------
__global__ __launch_bounds__(256, 3) void k_vq32(
    const float* __restrict__ MT, const float* __restrict__ VT,
    const float* __restrict__ noise,
    const _Float16* __restrict__ CBh, const _Float16* __restrict__ CBl,
    const float* __restrict__ cn, const float* __restrict__ CB,
    float* __restrict__ out, float* __restrict__ losss)
{
    typedef float f32x16 __attribute__((ext_vector_type(16)));
    __shared__ _Float16 Zh[32 * 128];
    __shared__ _Float16 Zl[32 * 128];
    __shared__ float pb[4][32];
    __shared__ int   pi[4][32];
    __shared__ int   idx_s[32];
    __shared__ float red[4];

    const int tid = threadIdx.x;
    const int rowbase = blockIdx.x * 32;
    const int a = tid & 127;
    const int rhalf = tid >> 7;
    const int ga = a >> 3, ja = a & 7;

    for (int g = 0; g < 2; ++g) {
        float m1v[8], m2v[8], v1v[8], v2v[8], nzv[8];
        #pragma unroll
        for (int i = 0; i < 8; ++i) {
            int row = g * 16 + 2 * i + rhalf;
            int m = rowbase + row;
            int b = m / 372;
            int r1 = m + 12 * b;
            int r2 = r1 + 12;
            m1v[i] = MT[(size_t)r1 * ACT + a];
            m2v[i] = MT[(size_t)r2 * ACT + a];
            v1v[i] = VT[(size_t)r1 * ACT + a];
            v2v[i] = VT[(size_t)r2 * ACT + a];
            nzv[i] = noise[(size_t)m * ACT + a];
        }
        #pragma unroll
        for (int i = 0; i < 8; ++i) {
            int row = g * 16 + 2 * i + rhalf;
            int m = rowbase + row;
            float adm = m2v[i] - m1v[i];
            float adv = v2v[i] + v1v[i];
            float z = nzv[i] * sqrtf(adv + 1e-6f) + adm;
            int np = m / 12, s = m - np * 12;
            out[OFF_AD + (size_t)(np * 24 + s) * ACT + a] = adm;
            out[OFF_AD + (size_t)(np * 24 + 12 + s) * ACT + a] = adv;
            out[OFF_Z + (size_t)m * ACT + a] = z;
            _Float16 h = (_Float16)z;
            int ad = row * 128 + (((ga ^ (row & 15))) << 3) + ja;
            Zh[ad] = h;
            Zl[ad] = (_Float16)(z - (float)h);
        }
    }
    __syncthreads();

    const int w = tid >> 6, l = tid & 63;
    const int col = l & 31, hw = l >> 5;

    float best[16];
    int bidx[16];
    #pragma unroll
    for (int r = 0; r < 16; ++r) { best[r] = 3.4e38f; bidx[r] = 0; }

    for (int cc2 = 0; cc2 < 2; ++cc2) {
        f32x16 acc[4];
        #pragma unroll
        for (int t = 0; t < 4; ++t)
            #pragma unroll
            for (int r = 0; r < 16; ++r) acc[t][r] = 0.f;

        #pragma unroll
        for (int s = 0; s < 8; ++s) {
            int ad = col * 128 + (((s * 2 + hw) ^ (col & 15)) << 3);
            f16x8 ah = *(const f16x8*)&Zh[ad];
            f16x8 al = *(const f16x8*)&Zl[ad];
            #pragma unroll
            for (int t = 0; t < 4; ++t) {
                int tg = w * 8 + cc2 * 4 + t;
                f16x8 bh = *(const f16x8*)(CBh + ((size_t)(tg * 8 + s) * 64 + l) * 8);
                f16x8 bl = *(const f16x8*)(CBl + ((size_t)(tg * 8 + s) * 64 + l) * 8);
                acc[t] = __builtin_amdgcn_mfma_f32_32x32x16_f16(ah, bh, acc[t], 0, 0, 0);
                acc[t] = __builtin_amdgcn_mfma_f32_32x32x16_f16(ah, bl, acc[t], 0, 0, 0);
                acc[t] = __builtin_amdgcn_mfma_f32_32x32x16_f16(al, bh, acc[t], 0, 0, 0);
            }
        }

        float cnv[4];
        #pragma unroll
        for (int t = 0; t < 4; ++t) cnv[t] = cn[(w * 8 + cc2 * 4 + t) * 32 + col];

        #pragma unroll
        for (int reg = 0; reg < 16; ++reg) {
            #pragma unroll
            for (int t = 0; t < 4; ++t) {
                float d = cnv[t] - 2.f * acc[t][reg];
                int gi = (w * 8 + cc2 * 4 + t) * 32 + col;
                if (d < best[reg]) { best[reg] = d; bidx[reg] = gi; }
            }
        }
    }

    #pragma unroll
    for (int reg = 0; reg < 16; ++reg) {
        float bv_ = best[reg];
        int bi_ = bidx[reg];
        #pragma unroll
        for (int off = 1; off < 32; off <<= 1) {
            float ov = __shfl_xor(bv_, off, 64);
            int   oi = __shfl_xor(bi_, off, 64);
            if (ov < bv_ || (ov == bv_ && oi < bi_)) { bv_ = ov; bi_ = oi; }
        }
        if (col == 0) {
            int mrow = (reg & 3) + 8 * (reg >> 2) + 4 * hw;
            pb[w][mrow] = bv_;
            pi[w][mrow] = bi_;
        }
    }
    __syncthreads();

    if (tid < 32) {
        float bb = pb[0][tid];
        int bi_ = pi[0][tid];
        #pragma unroll
        for (int w2 = 1; w2 < 4; ++w2) {
            float v = pb[w2][tid];
            int ii = pi[w2][tid];
            if (v < bb || (v == bb && ii < bi_)) { bb = v; bi_ = ii; }
        }
        idx_s[tid] = bi_;
        out[OFF_IDX + rowbase + tid] = (float)bi_;
    }
    __syncthreads();

    float ls = 0.f;
    for (int g = 0; g < 2; ++g) {
        int civ[8]; float zv[8], qv[8];
        #pragma unroll
        for (int i = 0; i < 8; ++i) {
            int row = g * 16 + 2 * i + rhalf;
            civ[i] = idx_s[row];
            int ad = row * 128 + (((ga ^ (row & 15))) << 3) + ja;
            zv[i] = (float)Zh[ad] + (float)Zl[ad];
        }
        #pragma unroll
        for (int i = 0; i < 8; ++i) qv[i] = CB[(size_t)civ[i] * ACT + a];
        #pragma unroll
        for (int i = 0; i < 8; ++i) {
            int row = g * 16 + 2 * i + rhalf;
            size_t m = (size_t)(rowbase + row);
            float diff = zv[i] - qv[i];
            out[OFF_QS + m * ACT + a] = zv[i] + (qv[i] - zv[i]);
            out[OFF_AV + m * ACT + a] = diff;
            ls = fmaf(diff, diff, ls);
        }
    }
    #pragma unroll
    for (int off = 32; off; off >>= 1) ls += __shfl_xor(ls, off, 64);
    if (l == 0) red[w] = ls;
    __syncthreads();
    if (tid == 0) atomicAdd(losss, red[0] + red[1] + red[2] + red[3]);
}

__global__ void k_losses(const float* __restrict__ losss, float* __restrict__ out)
{
    float v = *losss * (1.f / 6094848.f);
    out[OFF_QL] = v;
    out[OFF_CL] = v;
}

extern "C" void kernel_launch(void* const* d_in, const int* in_sizes, int n_in,
                              void* d_out, int out_size, void* d_ws, size_t ws_size,
                              hipStream_t stream)
{
    const float* slots = (const float*)d_in[0];
    const float* noise = (const float*)d_in[1];
    const float* W1    = (const float*)d_in[2];
    const float* b1    = (const float*)d_in[3];
    const float* ln_g  = (const float*)d_in[4];
    const float* ln_b  = (const float*)d_in[5];
    const float* W2    = (const float*)d_in[6];
    const float* b2    = (const float*)d_in[7];
    const float* Wm    = (const float*)d_in[8];
    const float* bm    = (const float*)d_in[9];
    const float* Wv    = (const float*)d_in[10];
    const float* bv    = (const float*)d_in[11];
    const float* CB    = (const float*)d_in[12];
    float* out = (float*)d_out;
    float* ws  = (float*)d_ws;

    // workspace layout (floats): GH chunk (RC*1024) | MT | VT | weights block
    _Float16* GHh = (_Float16*)ws;
    _Float16* GHl = (_Float16*)(ws + (size_t)RC * 512);
    float* MT = ws + (size_t)RC * 1024;
    float* VT = MT + 6291456;
    float* wb = VT + 6291456;
    _Float16* W1h = (_Float16*)(wb + 0);
    _Float16* W1l = (_Float16*)(wb + 131072);
    _Float16* W2h = (_Float16*)(wb + 262144);
    _Float16* W2l = (_Float16*)(wb + 393216);
    _Float16* Wmh = (_Float16*)(wb + 524288);
    _Float16* Wml = (_Float16*)(wb + 540672);
    _Float16* Wvh = (_Float16*)(wb + 557056);
    _Float16* Wvl = (_Float16*)(wb + 573440);
    _Float16* CBh = (_Float16*)(wb + 589824);
    _Float16* CBl = (_Float16*)(wb + 655360);
    float* cn    = wb + 720896;
    float* v0    = wb + 721920;
    float* v1    = wb + 722176;
    float* losss = wb + 722432;
    float* stats = wb + 722688;   // 16 * R_ROWS * 2

    hipLaunchKernelGGL(k_packall, dim3(2821), dim3(256), 0, stream,
                       W1, W2, Wm, Wv, CB, ln_g, ln_b, b2,
                       W1h, W1l, W2h, W2l, Wmh, Wml, Wvh, Wvl, CBh, CBl,
                       cn, v0, v1, losss);

    for (int c = 0; c < NCHUNK; ++c) {
        int row0 = c * RC;
        hipLaunchKernelGGL(k_gemm1, dim3((RC / 256) * 16), dim3(1024), 0, stream,
                           slots, b1, W1h, W1l, GHh, GHl, stats, row0);
        hipLaunchKernelGGL(k_gemm2, dim3(RC / 32), dim3(512), 0, stream,
                           GHh, GHl, W2h, W2l, Wmh, Wml, Wvh, Wvl,
                           stats, v0, v1, bm, bv, MT, VT, row0);
    }

    hipLaunchKernelGGL(k_vq32, dim3(M_ROWS / 32), dim3(256), 0, stream,
                       MT, VT, noise, CBh, CBl, cn, CB, out, losss);
    hipLaunchKernelGGL(k_losses, dim3(1), dim3(1), 0, stream, losss, out);
}

// Round 13
// 443.905 us; speedup vs baseline: 1.2558x; 1.1419x over previous
//
#include <hip/hip_runtime.h>
#include <math.h>

#define R_ROWS 49152      // B*N*S = 128*32*12
#define HID 1024
#define SLOT 256
#define EMB 256
#define ACT 128
#define NCODE 1024
#define M_ROWS 47616      // B*(N-1)*S = 128*31*12

// output offsets (float elements)
#define OFF_AD 0
#define OFF_Z  12189696
#define OFF_AV 18284544
#define OFF_QS 24379392
#define OFF_IDX 30474240
#define OFF_QL 30521856
#define OFF_CL 30521857

// workspace offsets (float elements) — total ~25.9M floats = 103.6 MB
#define WS_XH    0
#define WS_XL    6291456
#define WS_MT   12582912
#define WS_VT   18874368
#define WS_W1H  25165824
#define WS_W1L  25296896
#define WS_W2H  25427968
#define WS_W2L  25559040
#define WS_WMH  25690112
#define WS_WML  25706496
#define WS_WVH  25722880
#define WS_WVL  25739264
#define WS_CBH  25755648
#define WS_CBL  25821184
#define WS_CN   25886720
#define WS_LOSS 25887744

typedef _Float16 f16x8 __attribute__((ext_vector_type(8)));
typedef float f32x4 __attribute__((ext_vector_type(4)));

// ---------------- fused pack kernel ----------------
// blocks: [0,1024) W1 | [1024,2048) W2 | [2048,2176) Wm | [2176,2304) Wv
//         [2304,2816) CB | [2816,2820) cn | [2820,8964) X row-major fp16 pack
__device__ __forceinline__ void pack_body(
    const float* __restrict__ W, _Float16* __restrict__ hi, _Float16* __restrict__ lo,
    int lgS, int N, int p)
{
    int j = p & 7;
    int l = (p >> 3) & 63;
    int q = p >> 9;
    int s = q & ((1 << lgS) - 1);
    int t = q >> lgS;
    int n = t * 16 + (l & 15);
    int k = s * 32 + ((l >> 4) << 3) + j;
    float x = W[(size_t)k * N + n];
    _Float16 h = (_Float16)x;
    hi[p] = h;
    lo[p] = (_Float16)(x - (float)h);
}

__global__ __launch_bounds__(256) void k_packall(
    const float* __restrict__ W1, const float* __restrict__ W2,
    const float* __restrict__ Wm, const float* __restrict__ Wv,
    const float* __restrict__ CB, const float* __restrict__ X,
    _Float16* __restrict__ W1h, _Float16* __restrict__ W1l,
    _Float16* __restrict__ W2h, _Float16* __restrict__ W2l,
    _Float16* __restrict__ Wmh, _Float16* __restrict__ Wml,
    _Float16* __restrict__ Wvh, _Float16* __restrict__ Wvl,
    _Float16* __restrict__ CBh, _Float16* __restrict__ CBl,
    _Float16* __restrict__ Xh, _Float16* __restrict__ Xl,
    float* __restrict__ cn, float* __restrict__ losss)
{
    const int bi = blockIdx.x;
    const int tid = threadIdx.x;
    if (bi == 0 && tid == 0) *losss = 0.f;

    if (bi < 1024) {
        pack_body(W1, W1h, W1l, 3, HID, bi * 256 + tid);
    } else if (bi < 2048) {
        pack_body(W2, W2h, W2l, 5, EMB, (bi - 1024) * 256 + tid);
    } else if (bi < 2176) {
        pack_body(Wm, Wmh, Wml, 3, ACT, (bi - 2048) * 256 + tid);
    } else if (bi < 2304) {
        pack_body(Wv, Wvh, Wvl, 3, ACT, (bi - 2176) * 256 + tid);
    } else if (bi < 2816) {
        // codebook pack for 32x32x16 B-fragments
        int p = (bi - 2304) * 256 + tid;
        int j = p & 7;
        int l = (p >> 3) & 63;
        int q = p >> 9;
        int s = q & 7;
        int t = q >> 3;
        int n = t * 32 + (l & 31);
        int k = s * 16 + ((l >> 5) << 3) + j;
        float x = CB[(size_t)n * ACT + k];
        _Float16 h = (_Float16)x;
        CBh[p] = h;
        CBl[p] = (_Float16)(x - (float)h);
    } else if (bi < 2820) {
        int c = (bi - 2816) * 256 + tid;
        float s = 0.f;
        #pragma unroll
        for (int k = 0; k < ACT; k += 4) {
            float4 v = *(const float4*)&CB[(size_t)c * ACT + k];
            s += v.x*v.x + v.y*v.y + v.z*v.z + v.w*v.w;
        }
        cn[c] = s;
    } else {
        // X pack: 8 elems/thread, row-major fp16 hi/lo
        size_t e0 = ((size_t)(bi - 2820) * 256 + tid) * 8;
        float4 va = *(const float4*)&X[e0];
        float4 vb = *(const float4*)&X[e0 + 4];
        float xv[8] = {va.x, va.y, va.z, va.w, vb.x, vb.y, vb.z, vb.w};
        f16x8 h8, l8;
        #pragma unroll
        for (int e = 0; e < 8; ++e) {
            _Float16 h = (_Float16)xv[e];
            h8[e] = h;
            l8[e] = (_Float16)(xv[e] - (float)h);
        }
        *(f16x8*)&Xh[e0] = h8;
        *(f16x8*)&Xl[e0] = l8;
    }
}

// ---------------- encoder: 512 threads / 8 waves, 16 rows/block (R5 exact) ----
__global__ __launch_bounds__(512, 4) void k_encoder_mfma(
    const _Float16* __restrict__ Xh, const _Float16* __restrict__ Xl,
    const float* __restrict__ b1, const float* __restrict__ ln_g, const float* __restrict__ ln_b,
    const float* __restrict__ b2, const float* __restrict__ bm, const float* __restrict__ bv,
    const _Float16* __restrict__ W1h, const _Float16* __restrict__ W1l,
    const _Float16* __restrict__ W2h, const _Float16* __restrict__ W2l,
    const _Float16* __restrict__ Wmh, const _Float16* __restrict__ Wml,
    const _Float16* __restrict__ Wvh, const _Float16* __restrict__ Wvl,
    float* __restrict__ MT, float* __restrict__ VT)
{
    __shared__ _Float16 Hh0[16][1024];   // 32 KB (hi); aliased for stats + E tile
    __shared__ _Float16 Hh1[16][1024];   // 32 KB (lo)

    const int tid = threadIdx.x;
    const int w  = tid >> 6;      // 0..7
    const int l  = tid & 63;
    const int lr = l & 15;
    const int lg = l >> 4;
    const long rowbase = (long)blockIdx.x * 16;

    // A fragments straight from packed X (no conversion VALU)
    f16x8 a0[8], a1[8];
    {
        const _Float16* xh = Xh + (size_t)(rowbase + lr) * SLOT + lg * 8;
        const _Float16* xl = Xl + (size_t)(rowbase + lr) * SLOT + lg * 8;
        #pragma unroll
        for (int s = 0; s < 8; ++s) {
            a0[s] = *(const f16x8*)&xh[32 * s];
            a1[s] = *(const f16x8*)&xl[32 * s];
        }
    }

    // GEMM1: wave w owns H cols [128w, 128w+128)
    f32x4 acc[8];
    #pragma unroll
    for (int t = 0; t < 8; ++t) acc[t] = (f32x4){0.f, 0.f, 0.f, 0.f};

    #pragma unroll
    for (int s = 0; s < 8; ++s) {
        #pragma unroll
        for (int t = 0; t < 8; ++t) {
            int tg = w * 8 + t;
            f16x8 bh = *(const f16x8*)(W1h + ((size_t)(tg * 8 + s) * 64 + l) * 8);
            f16x8 bl = *(const f16x8*)(W1l + ((size_t)(tg * 8 + s) * 64 + l) * 8);
            acc[t] = __builtin_amdgcn_mfma_f32_16x16x32_f16(a0[s], bh, acc[t], 0, 0, 0);
            acc[t] = __builtin_amdgcn_mfma_f32_16x16x32_f16(a0[s], bl, acc[t], 0, 0, 0);
            acc[t] = __builtin_amdgcn_mfma_f32_16x16x32_f16(a1[s], bh, acc[t], 0, 0, 0);
        }
    }

    // bias + ReLU
    #pragma unroll
    for (int t = 0; t < 8; ++t) {
        float bb = b1[w * 128 + t * 16 + lr];
        #pragma unroll
        for (int r = 0; r < 4; ++r) acc[t][r] = fmaxf(acc[t][r] + bb, 0.f);
    }

    // LayerNorm stats: per-wave partials, 16-lane shuffle, cross-wave via LDS
    float sum[4] = {0,0,0,0}, sq[4] = {0,0,0,0};
    #pragma unroll
    for (int t = 0; t < 8; ++t)
        #pragma unroll
        for (int r = 0; r < 4; ++r) {
            float v = acc[t][r];
            sum[r] += v; sq[r] = fmaf(v, v, sq[r]);
        }
    #pragma unroll
    for (int off = 1; off < 16; off <<= 1)
        #pragma unroll
        for (int r = 0; r < 4; ++r) {
            sum[r] += __shfl_xor(sum[r], off, 64);
            sq[r]  += __shfl_xor(sq[r],  off, 64);
        }
    float* stat = (float*)&Hh0[0][0];   // [0..127]=sum, [128..255]=sq
    if (lr == 0) {
        #pragma unroll
        for (int r = 0; r < 4; ++r) {
            stat[w * 16 + 4 * lg + r]       = sum[r];
            stat[128 + w * 16 + 4 * lg + r] = sq[r];
        }
    }
    __syncthreads();
    float mu[4], rs[4];
    #pragma unroll
    for (int r = 0; r < 4; ++r) {
        int m = 4 * lg + r;
        float s = 0.f, q = 0.f;
        #pragma unroll
        for (int wv = 0; wv < 8; ++wv) {
            s += stat[wv * 16 + m];
            q += stat[128 + wv * 16 + m];
        }
        float mmu = s * (1.f / HID);
        float var = q * (1.f / HID) - mmu * mmu;
        mu[r] = mmu;
        rs[r] = 1.f / sqrtf(var + 1e-5f);
    }
    __syncthreads();

    // normalize, split, store swizzled
    #pragma unroll
    for (int t = 0; t < 8; ++t) {
        int n = w * 128 + t * 16 + lr;
        float g = ln_g[n], be = ln_b[n];
        #pragma unroll
        for (int r = 0; r < 4; ++r) {
            int m = 4 * lg + r;
            float v = (acc[t][r] - mu[r]) * rs[r] * g + be;
            _Float16 h = (_Float16)v;
            _Float16 lo = (_Float16)(v - (float)h);
            int c = n >> 3, jj = n & 7;
            int cs = c ^ (m & 7);
            Hh0[m][cs * 8 + jj] = h;
            Hh1[m][cs * 8 + jj] = lo;
        }
    }
    __syncthreads();

    // GEMM2: wave w owns E cols [32w, 32w+32)
    f32x4 acc2[2];
    #pragma unroll
    for (int t = 0; t < 2; ++t) acc2[t] = (f32x4){0.f, 0.f, 0.f, 0.f};

    #pragma unroll 4
    for (int s = 0; s < 32; ++s) {
        int cs = (4 * s + lg) ^ (lr & 7);
        f16x8 ah = *(const f16x8*)&Hh0[lr][cs * 8];
        f16x8 al = *(const f16x8*)&Hh1[lr][cs * 8];
        #pragma unroll
        for (int t = 0; t < 2; ++t) {
            int tg = w * 2 + t;
            f16x8 bh = *(const f16x8*)(W2h + ((size_t)(tg * 32 + s) * 64 + l) * 8);
            f16x8 bl = *(const f16x8*)(W2l + ((size_t)(tg * 32 + s) * 64 + l) * 8);
            acc2[t] = __builtin_amdgcn_mfma_f32_16x16x32_f16(ah, bh, acc2[t], 0, 0, 0);
            acc2[t] = __builtin_amdgcn_mfma_f32_16x16x32_f16(ah, bl, acc2[t], 0, 0, 0);
            acc2[t] = __builtin_amdgcn_mfma_f32_16x16x32_f16(al, bh, acc2[t], 0, 0, 0);
        }
    }
    __syncthreads();

    // E tile (+b2) -> fp16x2, swizzled, aliased into Hh0
    _Float16* Es0 = &Hh0[0][0];          // 16x256
    _Float16* Es1 = &Hh0[0][0] + 4096;   // 16x256
    #pragma unroll
    for (int t = 0; t < 2; ++t) {
        int n = w * 32 + t * 16 + lr;
        float bb2 = b2[n];
        #pragma unroll
        for (int r = 0; r < 4; ++r) {
            int m = 4 * lg + r;
            float v = acc2[t][r] + bb2;
            _Float16 h = (_Float16)v;
            _Float16 lo = (_Float16)(v - (float)h);
            int c = n >> 3, jj = n & 7;
            int cs = c ^ (m & 7);
            Es0[m * 256 + cs * 8 + jj] = h;
            Es1[m * 256 + cs * 8 + jj] = lo;
        }
    }
    __syncthreads();

    // heads: waves 0..3 -> MT cols 32(w&3).., waves 4..7 -> VT
    const _Float16* WXh = (w < 4) ? Wmh : Wvh;
    const _Float16* WXl = (w < 4) ? Wml : Wvl;
    f32x4 acc3[2];
    #pragma unroll
    for (int t = 0; t < 2; ++t) acc3[t] = (f32x4){0.f, 0.f, 0.f, 0.f};

    #pragma unroll
    for (int s = 0; s < 8; ++s) {
        int cs = (4 * s + lg) ^ (lr & 7);
        f16x8 ah = *(const f16x8*)&Es0[lr * 256 + cs * 8];
        f16x8 al = *(const f16x8*)&Es1[lr * 256 + cs * 8];
        #pragma unroll
        for (int t = 0; t < 2; ++t) {
            int tg = (w & 3) * 2 + t;
            f16x8 bh = *(const f16x8*)(WXh + ((size_t)(tg * 8 + s) * 64 + l) * 8);
            f16x8 bl = *(const f16x8*)(WXl + ((size_t)(tg * 8 + s) * 64 + l) * 8);
            acc3[t] = __builtin_amdgcn_mfma_f32_16x16x32_f16(ah, bh, acc3[t], 0, 0, 0);
            acc3[t] = __builtin_amdgcn_mfma_f32_16x16x32_f16(ah, bl, acc3[t], 0, 0, 0);
            acc3[t] = __builtin_amdgcn_mfma_f32_16x16x32_f16(al, bh, acc3[t], 0, 0, 0);
        }
    }

    #pragma unroll
    for (int t = 0; t < 2; ++t) {
        int a = (w & 3) * 32 + t * 16 + lr;
        float bx = (w < 4) ? bm[a] : bv[a];
        #pragma unroll
        for (int r = 0; r < 4; ++r) {
            float v = acc3[t][r] + bx;
            size_t row = rowbase + 4 * lg + r;
            if (w < 4) MT[row * ACT + a] = v;
            else       VT[row * ACT + a] = fabsf(v);
        }
    }
}

// ---------------- fused action + VQ + finalize (R5 exact) ----------------
// 372 blocks x 256 threads; each block owns 128 consecutive m-rows.
__global__ __launch_bounds__(256, 2) void k_vqfused(
    const float* __restrict__ MT, const float* __restrict__ VT,
    const float* __restrict__ noise,
    const _Float16* __restrict__ CBh, const _Float16* __restrict__ CBl,
    const float* __restrict__ cn, const float* __restrict__ CB,
    float* __restrict__ out, float* __restrict__ losss)
{
    typedef float f32x16 __attribute__((ext_vector_type(16)));
    __shared__ float4 Zs4[4096];         // 64 KB: z[128][128], XOR-swizzled float4s
    __shared__ int   idx_s[128];
    __shared__ float red[4];
    float* Zs = (float*)Zs4;

    const int tid = threadIdx.x;
    const int rowbase = blockIdx.x * 128;
    const int a = tid & 127;
    const int rhalf = tid >> 7;

    // ---- phase 1: z = noise*sqrt(adv+eps)+adm; write AD + Z outputs; stash z in LDS ----
    #pragma unroll 8
    for (int i = 0; i < 64; ++i) {
        int row = 2 * i + rhalf;
        int m = rowbase + row;
        int b = m / 372;
        int r1 = m + 12 * b;
        int r2 = r1 + 12;
        float m1 = MT[(size_t)r1 * ACT + a], m2 = MT[(size_t)r2 * ACT + a];
        float v1 = VT[(size_t)r1 * ACT + a], v2 = VT[(size_t)r2 * ACT + a];
        float adm = m2 - m1;
        float adv = v2 + v1;
        float z = noise[(size_t)m * ACT + a] * sqrtf(adv + 1e-6f) + adm;
        int np = m / 12, s = m - np * 12;
        out[OFF_AD + (size_t)(np * 24 + s) * ACT + a] = adm;
        out[OFF_AD + (size_t)(np * 24 + 12 + s) * ACT + a] = adv;
        out[OFF_Z + (size_t)m * ACT + a] = z;
        Zs[row * 128 + (((a >> 2) ^ (row & 31)) << 2) + (a & 3)] = z;
    }
    __syncthreads();

    // ---- phase 2: A fragments from LDS (wave w owns rows [32w,32w+32)) ----
    const int w = tid >> 6, l = tid & 63;
    const int col = l & 31, hw = l >> 5;
    const int arow = 32 * w + col;

    f16x8 a0[8], a1[8];
    #pragma unroll
    for (int s = 0; s < 8; ++s) {
        #pragma unroll
        for (int half = 0; half < 2; ++half) {
            int k4 = s * 4 + hw * 2 + half;   // float4 index along k
            float4 v = *(const float4*)&Zs[arow * 128 + ((k4 ^ (arow & 31)) << 2)];
            float xv[4] = {v.x, v.y, v.z, v.w};
            #pragma unroll
            for (int e = 0; e < 4; ++e) {
                _Float16 h = (_Float16)xv[e];
                a0[s][half * 4 + e] = h;
                a1[s][half * 4 + e] = (_Float16)(xv[e] - (float)h);
            }
        }
    }

    // ---- phase 3: distances over 4 codebook chunks, running argmin ----
    float best[16];
    int bidx[16];
    #pragma unroll
    for (int r = 0; r < 16; ++r) { best[r] = 3.4e38f; bidx[r] = 0; }

    for (int cb = 0; cb < 4; ++cb) {
        f32x16 acc[8];
        #pragma unroll
        for (int t = 0; t < 8; ++t)
            #pragma unroll
            for (int r = 0; r < 16; ++r) acc[t][r] = 0.f;

        #pragma unroll
        for (int s = 0; s < 8; ++s) {
            #pragma unroll
            for (int t = 0; t < 8; ++t) {
                int tg = cb * 8 + t;
                f16x8 bh = *(const f16x8*)(CBh + ((size_t)(tg * 8 + s) * 64 + l) * 8);
                f16x8 bl = *(const f16x8*)(CBl + ((size_t)(tg * 8 + s) * 64 + l) * 8);
                acc[t] = __builtin_amdgcn_mfma_f32_32x32x16_f16(a0[s], bh, acc[t], 0, 0, 0);
                acc[t] = __builtin_amdgcn_mfma_f32_32x32x16_f16(a0[s], bl, acc[t], 0, 0, 0);
                acc[t] = __builtin_amdgcn_mfma_f32_32x32x16_f16(a1[s], bh, acc[t], 0, 0, 0);
            }
        }

        float cnv[8];
        #pragma unroll
        for (int t = 0; t < 8; ++t) cnv[t] = cn[cb * 256 + t * 32 + col];

        #pragma unroll
        for (int reg = 0; reg < 16; ++reg) {
            #pragma unroll
            for (int t = 0; t < 8; ++t) {
                float d = cnv[t] - 2.f * acc[t][reg];
                int gi = cb * 256 + t * 32 + col;
                if (d < best[reg]) { best[reg] = d; bidx[reg] = gi; }
            }
        }
    }

    // reduce over the 32 cols; C row = (reg&3)+8*(reg>>2)+4*hw
    #pragma unroll
    for (int reg = 0; reg < 16; ++reg) {
        float bv_ = best[reg];
        int bi_ = bidx[reg];
        #pragma unroll
        for (int off = 1; off < 32; off <<= 1) {
            float ov = __shfl_xor(bv_, off, 64);
            int   oi = __shfl_xor(bi_, off, 64);
            if (ov < bv_ || (ov == bv_ && oi < bi_)) { bv_ = ov; bi_ = oi; }
        }
        if (col == 0) {
            int mloc = 32 * w + (reg & 3) + 8 * (reg >> 2) + 4 * hw;
            idx_s[mloc] = bi_;
            out[OFF_IDX + rowbase + mloc] = (float)bi_;
        }
    }
    __syncthreads();

    // ---- phase 4: gather q, write QS/AV, block loss ----
    float ls = 0.f;
    #pragma unroll 8
    for (int i = 0; i < 64; ++i) {
        int row = 2 * i + rhalf;
        float z = Zs[row * 128 + (((a >> 2) ^ (row & 31)) << 2) + (a & 3)];
        int ci = idx_s[row];
        float q = CB[(size_t)ci * ACT + a];
        float diff = z - q;
        size_t m = (size_t)(rowbase + row);
        out[OFF_QS + m * ACT + a] = z + (q - z);
        out[OFF_AV + m * ACT + a] = diff;
        ls = fmaf(diff, diff, ls);
    }
    #pragma unroll
    for (int off = 32; off; off >>= 1) ls += __shfl_xor(ls, off, 64);
    if (l == 0) red[w] = ls;
    __syncthreads();
    if (tid == 0) atomicAdd(losss, red[0] + red[1] + red[2] + red[3]);
}

__global__ void k_losses(const float* __restrict__ losss, float* __restrict__ out)
{
    float v = *losss * (1.f / 6094848.f);
    out[OFF_QL] = v;
    out[OFF_CL] = v;
}

extern "C" void kernel_launch(void* const* d_in, const int* in_sizes, int n_in,
                              void* d_out, int out_size, void* d_ws, size_t ws_size,
                              hipStream_t stream)
{
    const float* slots = (const float*)d_in[0];
    const float* noise = (const float*)d_in[1];
    const float* W1    = (const float*)d_in[2];
    const float* b1    = (const float*)d_in[3];
    const float* ln_g  = (const float*)d_in[4];
    const float* ln_b  = (const float*)d_in[5];
    const float* W2    = (const float*)d_in[6];
    const float* b2    = (const float*)d_in[7];
    const float* Wm    = (const float*)d_in[8];
    const float* bm    = (const float*)d_in[9];
    const float* Wv    = (const float*)d_in[10];
    const float* bv    = (const float*)d_in[11];
    const float* CB    = (const float*)d_in[12];
    float* out = (float*)d_out;
    float* ws  = (float*)d_ws;

    float* MT    = ws + WS_MT;
    float* VT    = ws + WS_VT;
    float* cn    = ws + WS_CN;
    float* losss = ws + WS_LOSS;

    _Float16* Xh  = (_Float16*)(ws + WS_XH);
    _Float16* Xl  = (_Float16*)(ws + WS_XL);
    _Float16* W1h = (_Float16*)(ws + WS_W1H);
    _Float16* W1l = (_Float16*)(ws + WS_W1L);
    _Float16* W2h = (_Float16*)(ws + WS_W2H);
    _Float16* W2l = (_Float16*)(ws + WS_W2L);
    _Float16* Wmh = (_Float16*)(ws + WS_WMH);
    _Float16* Wml = (_Float16*)(ws + WS_WML);
    _Float16* Wvh = (_Float16*)(ws + WS_WVH);
    _Float16* Wvl = (_Float16*)(ws + WS_WVL);
    _Float16* CBh = (_Float16*)(ws + WS_CBH);
    _Float16* CBl = (_Float16*)(ws + WS_CBL);

    hipLaunchKernelGGL(k_packall, dim3(8964), dim3(256), 0, stream,
                       W1, W2, Wm, Wv, CB, slots,
                       W1h, W1l, W2h, W2l, Wmh, Wml, Wvh, Wvl, CBh, CBl,
                       Xh, Xl, cn, losss);
    hipLaunchKernelGGL(k_encoder_mfma, dim3(R_ROWS/16), dim3(512), 0, stream,
                       Xh, Xl, b1, ln_g, ln_b, b2, bm, bv,
                       W1h, W1l, W2h, W2l, Wmh, Wml, Wvh, Wvl, MT, VT);
    hipLaunchKernelGGL(k_vqfused, dim3(M_ROWS/128), dim3(256), 0, stream,
                       MT, VT, noise, CBh, CBl, cn, CB, out, losss);
    hipLaunchKernelGGL(k_losses, dim3(1), dim3(1), 0, stream, losss, out);
}

// Round 14
// 404.833 us; speedup vs baseline: 1.3770x; 1.0965x over previous
//
#include <hip/hip_runtime.h>
#include <math.h>

#define R_ROWS 49152      // B*N*S = 128*32*12
#define HID 1024
#define SLOT 256
#define EMB 256
#define ACT 128
#define NCODE 1024
#define M_ROWS 47616      // B*(N-1)*S = 128*31*12

// output offsets (float elements)
#define OFF_AD 0
#define OFF_Z  12189696
#define OFF_AV 18284544
#define OFF_QS 24379392
#define OFF_IDX 30474240
#define OFF_QL 30521856
#define OFF_CL 30521857

// workspace offsets (float elements) — total ~25.9M floats = 103.6 MB
#define WS_XH    0
#define WS_XL    6291456
#define WS_MT   12582912
#define WS_VT   18874368
#define WS_W1H  25165824
#define WS_W1L  25296896
#define WS_W2H  25427968
#define WS_W2L  25559040
#define WS_WMH  25690112
#define WS_WML  25706496
#define WS_WVH  25722880
#define WS_WVL  25739264
#define WS_CBH  25755648
#define WS_CBL  25821184
#define WS_CN   25886720
#define WS_LOSS 25887744

typedef _Float16 f16x8 __attribute__((ext_vector_type(8)));
typedef float f32x4 __attribute__((ext_vector_type(4)));

// ---------------- fused pack kernel (R13 exact) ----------------
__device__ __forceinline__ void pack_body(
    const float* __restrict__ W, _Float16* __restrict__ hi, _Float16* __restrict__ lo,
    int lgS, int N, int p)
{
    int j = p & 7;
    int l = (p >> 3) & 63;
    int q = p >> 9;
    int s = q & ((1 << lgS) - 1);
    int t = q >> lgS;
    int n = t * 16 + (l & 15);
    int k = s * 32 + ((l >> 4) << 3) + j;
    float x = W[(size_t)k * N + n];
    _Float16 h = (_Float16)x;
    hi[p] = h;
    lo[p] = (_Float16)(x - (float)h);
}

__global__ __launch_bounds__(256) void k_packall(
    const float* __restrict__ W1, const float* __restrict__ W2,
    const float* __restrict__ Wm, const float* __restrict__ Wv,
    const float* __restrict__ CB, const float* __restrict__ X,
    _Float16* __restrict__ W1h, _Float16* __restrict__ W1l,
    _Float16* __restrict__ W2h, _Float16* __restrict__ W2l,
    _Float16* __restrict__ Wmh, _Float16* __restrict__ Wml,
    _Float16* __restrict__ Wvh, _Float16* __restrict__ Wvl,
    _Float16* __restrict__ CBh, _Float16* __restrict__ CBl,
    _Float16* __restrict__ Xh, _Float16* __restrict__ Xl,
    float* __restrict__ cn, float* __restrict__ losss)
{
    const int bi = blockIdx.x;
    const int tid = threadIdx.x;
    if (bi == 0 && tid == 0) *losss = 0.f;

    if (bi < 1024) {
        pack_body(W1, W1h, W1l, 3, HID, bi * 256 + tid);
    } else if (bi < 2048) {
        pack_body(W2, W2h, W2l, 5, EMB, (bi - 1024) * 256 + tid);
    } else if (bi < 2176) {
        pack_body(Wm, Wmh, Wml, 3, ACT, (bi - 2048) * 256 + tid);
    } else if (bi < 2304) {
        pack_body(Wv, Wvh, Wvl, 3, ACT, (bi - 2176) * 256 + tid);
    } else if (bi < 2816) {
        int p = (bi - 2304) * 256 + tid;
        int j = p & 7;
        int l = (p >> 3) & 63;
        int q = p >> 9;
        int s = q & 7;
        int t = q >> 3;
        int n = t * 32 + (l & 31);
        int k = s * 16 + ((l >> 5) << 3) + j;
        float x = CB[(size_t)n * ACT + k];
        _Float16 h = (_Float16)x;
        CBh[p] = h;
        CBl[p] = (_Float16)(x - (float)h);
    } else if (bi < 2820) {
        int c = (bi - 2816) * 256 + tid;
        float s = 0.f;
        #pragma unroll
        for (int k = 0; k < ACT; k += 4) {
            float4 v = *(const float4*)&CB[(size_t)c * ACT + k];
            s += v.x*v.x + v.y*v.y + v.z*v.z + v.w*v.w;
        }
        cn[c] = s;
    } else {
        size_t e0 = ((size_t)(bi - 2820) * 256 + tid) * 8;
        float4 va = *(const float4*)&X[e0];
        float4 vb = *(const float4*)&X[e0 + 4];
        float xv[8] = {va.x, va.y, va.z, va.w, vb.x, vb.y, vb.z, vb.w};
        f16x8 h8, l8;
        #pragma unroll
        for (int e = 0; e < 8; ++e) {
            _Float16 h = (_Float16)xv[e];
            h8[e] = h;
            l8[e] = (_Float16)(xv[e] - (float)h);
        }
        *(f16x8*)&Xh[e0] = h8;
        *(f16x8*)&Xl[e0] = l8;
    }
}

// ---------------- encoder: 1024 threads / 16 waves, 32 rows/block ----------------
// Halves per-row weight traffic vs 16-row blocks; same 16 waves/CU occupancy.
__global__ __launch_bounds__(1024, 4) void k_encoder_mfma(
    const _Float16* __restrict__ Xh, const _Float16* __restrict__ Xl,
    const float* __restrict__ b1, const float* __restrict__ ln_g, const float* __restrict__ ln_b,
    const float* __restrict__ b2, const float* __restrict__ bm, const float* __restrict__ bv,
    const _Float16* __restrict__ W1h, const _Float16* __restrict__ W1l,
    const _Float16* __restrict__ W2h, const _Float16* __restrict__ W2l,
    const _Float16* __restrict__ Wmh, const _Float16* __restrict__ Wml,
    const _Float16* __restrict__ Wvh, const _Float16* __restrict__ Wvl,
    float* __restrict__ MT, float* __restrict__ VT)
{
    __shared__ _Float16 Hh0[32][1024];   // 64 KB (hi); E tile aliases here
    __shared__ _Float16 Hh1[32][1024];   // 64 KB (lo)
    __shared__ float stat_s[1024];       // [0..511]=sum by (w,row), [512..1023]=sq
    __shared__ float mu_s[32], rs_s[32];

    const int tid = threadIdx.x;
    const int w  = tid >> 6;      // 0..15
    const int l  = tid & 63;
    const int lr = l & 15;
    const int lg = l >> 4;
    const long rowbase = (long)blockIdx.x * 32;

    // ---- GEMM1: wave w owns H col-tiles tg = 4w..4w+3; both 16-row halves ----
    f32x4 acc1[2][4];
    #pragma unroll
    for (int rt = 0; rt < 2; ++rt)
        #pragma unroll
        for (int t = 0; t < 4; ++t) acc1[rt][t] = (f32x4){0.f, 0.f, 0.f, 0.f};

    #pragma unroll
    for (int s = 0; s < 8; ++s) {
        f16x8 a0[2], a1[2];
        #pragma unroll
        for (int rt = 0; rt < 2; ++rt) {
            size_t xoff = (size_t)(rowbase + rt * 16 + lr) * SLOT + s * 32 + lg * 8;
            a0[rt] = *(const f16x8*)&Xh[xoff];
            a1[rt] = *(const f16x8*)&Xl[xoff];
        }
        #pragma unroll
        for (int t = 0; t < 4; ++t) {
            int tg = w * 4 + t;
            f16x8 bh = *(const f16x8*)(W1h + ((size_t)(tg * 8 + s) * 64 + l) * 8);
            f16x8 bl = *(const f16x8*)(W1l + ((size_t)(tg * 8 + s) * 64 + l) * 8);
            #pragma unroll
            for (int rt = 0; rt < 2; ++rt) {
                acc1[rt][t] = __builtin_amdgcn_mfma_f32_16x16x32_f16(a0[rt], bh, acc1[rt][t], 0, 0, 0);
                acc1[rt][t] = __builtin_amdgcn_mfma_f32_16x16x32_f16(a0[rt], bl, acc1[rt][t], 0, 0, 0);
                acc1[rt][t] = __builtin_amdgcn_mfma_f32_16x16x32_f16(a1[rt], bh, acc1[rt][t], 0, 0, 0);
            }
        }
    }

    // bias + ReLU
    #pragma unroll
    for (int rt = 0; rt < 2; ++rt)
        #pragma unroll
        for (int t = 0; t < 4; ++t) {
            float bb = b1[(w * 4 + t) * 16 + lr];
            #pragma unroll
            for (int r = 0; r < 4; ++r) acc1[rt][t][r] = fmaxf(acc1[rt][t][r] + bb, 0.f);
        }

    // LN partial stats (per wave over its 64 cols), per row-half
    #pragma unroll
    for (int rt = 0; rt < 2; ++rt) {
        float sum[4] = {0,0,0,0}, sq[4] = {0,0,0,0};
        #pragma unroll
        for (int t = 0; t < 4; ++t)
            #pragma unroll
            for (int r = 0; r < 4; ++r) {
                float v = acc1[rt][t][r];
                sum[r] += v; sq[r] = fmaf(v, v, sq[r]);
            }
        #pragma unroll
        for (int off = 1; off < 16; off <<= 1)
            #pragma unroll
            for (int r = 0; r < 4; ++r) {
                sum[r] += __shfl_xor(sum[r], off, 64);
                sq[r]  += __shfl_xor(sq[r],  off, 64);
            }
        if (lr == 0) {
            #pragma unroll
            for (int r = 0; r < 4; ++r) {
                int row = rt * 16 + 4 * lg + r;
                stat_s[w * 32 + row]       = sum[r];
                stat_s[512 + w * 32 + row] = sq[r];
            }
        }
    }
    __syncthreads();

    if (tid < 32) {
        float s = 0.f, q = 0.f;
        #pragma unroll
        for (int wv = 0; wv < 16; ++wv) {
            s += stat_s[wv * 32 + tid];
            q += stat_s[512 + wv * 32 + tid];
        }
        float mu = s * (1.f / HID);
        float var = q * (1.f / HID) - mu * mu;
        mu_s[tid] = mu;
        rs_s[tid] = 1.f / sqrtf(var + 1e-5f);
    }
    __syncthreads();

    // normalize, split to fp16 hi/lo, write swizzled H
    float murow[2][4], rsrow[2][4];
    #pragma unroll
    for (int rt = 0; rt < 2; ++rt)
        #pragma unroll
        for (int r = 0; r < 4; ++r) {
            int row = rt * 16 + 4 * lg + r;
            murow[rt][r] = mu_s[row];
            rsrow[rt][r] = rs_s[row];
        }

    #pragma unroll
    for (int rt = 0; rt < 2; ++rt)
        #pragma unroll
        for (int t = 0; t < 4; ++t) {
            int n = (w * 4 + t) * 16 + lr;
            float g = ln_g[n], be = ln_b[n];
            int c = n >> 3, jj = n & 7;
            #pragma unroll
            for (int r = 0; r < 4; ++r) {
                int row = rt * 16 + 4 * lg + r;
                float v = (acc1[rt][t][r] - murow[rt][r]) * rsrow[rt][r] * g + be;
                _Float16 h = (_Float16)v;
                _Float16 lo = (_Float16)(v - (float)h);
                int cs = c ^ (row & 7);
                Hh0[row][cs * 8 + jj] = h;
                Hh1[row][cs * 8 + jj] = lo;
            }
        }
    __syncthreads();

    // ---- GEMM2: wave w owns E cols [16w, 16w+16); both row-halves ----
    f32x4 acc2[2];
    #pragma unroll
    for (int rt = 0; rt < 2; ++rt) acc2[rt] = (f32x4){0.f, 0.f, 0.f, 0.f};

    #pragma unroll 4
    for (int s = 0; s < 32; ++s) {
        f16x8 ah[2], al[2];
        #pragma unroll
        for (int rt = 0; rt < 2; ++rt) {
            int row = rt * 16 + lr;
            int cs = (s * 4 + lg) ^ (row & 7);
            ah[rt] = *(const f16x8*)&Hh0[row][cs * 8];
            al[rt] = *(const f16x8*)&Hh1[row][cs * 8];
        }
        f16x8 bh = *(const f16x8*)(W2h + ((size_t)(w * 32 + s) * 64 + l) * 8);
        f16x8 bl = *(const f16x8*)(W2l + ((size_t)(w * 32 + s) * 64 + l) * 8);
        #pragma unroll
        for (int rt = 0; rt < 2; ++rt) {
            acc2[rt] = __builtin_amdgcn_mfma_f32_16x16x32_f16(ah[rt], bh, acc2[rt], 0, 0, 0);
            acc2[rt] = __builtin_amdgcn_mfma_f32_16x16x32_f16(ah[rt], bl, acc2[rt], 0, 0, 0);
            acc2[rt] = __builtin_amdgcn_mfma_f32_16x16x32_f16(al[rt], bh, acc2[rt], 0, 0, 0);
        }
    }
    __syncthreads();   // H reads done before E overwrites Hh0

    // E tile (+b2) -> fp16 hi/lo, swizzled, aliased into Hh0
    _Float16* Es0 = &Hh0[0][0];          // 32x256
    _Float16* Es1 = &Hh0[0][0] + 8192;   // 32x256
    {
        int n = w * 16 + lr;
        float bb2 = b2[n];
        int c = n >> 3, jj = n & 7;
        #pragma unroll
        for (int rt = 0; rt < 2; ++rt) {
            #pragma unroll
            for (int r = 0; r < 4; ++r) {
                int row = rt * 16 + 4 * lg + r;
                float v = acc2[rt][r] + bb2;
                _Float16 h = (_Float16)v;
                _Float16 lo = (_Float16)(v - (float)h);
                int cs = c ^ (row & 7);
                Es0[row * 256 + cs * 8 + jj] = h;
                Es1[row * 256 + cs * 8 + jj] = lo;
            }
        }
    }
    __syncthreads();

    // ---- heads: waves 0..7 -> MT, 8..15 -> VT; wave owns 16 head-cols ----
    const int half = w >> 3;
    const int ct = w & 7;
    const _Float16* WXh = half ? Wvh : Wmh;
    const _Float16* WXl = half ? Wvl : Wml;
    f32x4 acc3[2];
    #pragma unroll
    for (int rt = 0; rt < 2; ++rt) acc3[rt] = (f32x4){0.f, 0.f, 0.f, 0.f};

    #pragma unroll
    for (int s = 0; s < 8; ++s) {
        f16x8 ah[2], al[2];
        #pragma unroll
        for (int rt = 0; rt < 2; ++rt) {
            int row = rt * 16 + lr;
            int cs = (s * 4 + lg) ^ (row & 7);
            ah[rt] = *(const f16x8*)&Es0[row * 256 + cs * 8];
            al[rt] = *(const f16x8*)&Es1[row * 256 + cs * 8];
        }
        f16x8 bh = *(const f16x8*)(WXh + ((size_t)(ct * 8 + s) * 64 + l) * 8);
        f16x8 bl = *(const f16x8*)(WXl + ((size_t)(ct * 8 + s) * 64 + l) * 8);
        #pragma unroll
        for (int rt = 0; rt < 2; ++rt) {
            acc3[rt] = __builtin_amdgcn_mfma_f32_16x16x32_f16(ah[rt], bh, acc3[rt], 0, 0, 0);
            acc3[rt] = __builtin_amdgcn_mfma_f32_16x16x32_f16(ah[rt], bl, acc3[rt], 0, 0, 0);
            acc3[rt] = __builtin_amdgcn_mfma_f32_16x16x32_f16(al[rt], bh, acc3[rt], 0, 0, 0);
        }
    }

    {
        int a = ct * 16 + lr;
        float bx = half ? bv[a] : bm[a];
        #pragma unroll
        for (int rt = 0; rt < 2; ++rt) {
            #pragma unroll
            for (int r = 0; r < 4; ++r) {
                float v = acc3[rt][r] + bx;
                size_t row = rowbase + rt * 16 + 4 * lg + r;
                if (half) VT[row * ACT + a] = fabsf(v);
                else      MT[row * ACT + a] = v;
            }
        }
    }
}

// ---------------- fused action + VQ + finalize (R13/R5 exact) ----------------
__global__ __launch_bounds__(256, 2) void k_vqfused(
    const float* __restrict__ MT, const float* __restrict__ VT,
    const float* __restrict__ noise,
    const _Float16* __restrict__ CBh, const _Float16* __restrict__ CBl,
    const float* __restrict__ cn, const float* __restrict__ CB,
    float* __restrict__ out, float* __restrict__ losss)
{
    typedef float f32x16 __attribute__((ext_vector_type(16)));
    __shared__ float4 Zs4[4096];
    __shared__ int   idx_s[128];
    __shared__ float red[4];
    float* Zs = (float*)Zs4;

    const int tid = threadIdx.x;
    const int rowbase = blockIdx.x * 128;
    const int a = tid & 127;
    const int rhalf = tid >> 7;

    #pragma unroll 8
    for (int i = 0; i < 64; ++i) {
        int row = 2 * i + rhalf;
        int m = rowbase + row;
        int b = m / 372;
        int r1 = m + 12 * b;
        int r2 = r1 + 12;
        float m1 = MT[(size_t)r1 * ACT + a], m2 = MT[(size_t)r2 * ACT + a];
        float v1 = VT[(size_t)r1 * ACT + a], v2 = VT[(size_t)r2 * ACT + a];
        float adm = m2 - m1;
        float adv = v2 + v1;
        float z = noise[(size_t)m * ACT + a] * sqrtf(adv + 1e-6f) + adm;
        int np = m / 12, s = m - np * 12;
        out[OFF_AD + (size_t)(np * 24 + s) * ACT + a] = adm;
        out[OFF_AD + (size_t)(np * 24 + 12 + s) * ACT + a] = adv;
        out[OFF_Z + (size_t)m * ACT + a] = z;
        Zs[row * 128 + (((a >> 2) ^ (row & 31)) << 2) + (a & 3)] = z;
    }
    __syncthreads();

    const int w = tid >> 6, l = tid & 63;
    const int col = l & 31, hw = l >> 5;
    const int arow = 32 * w + col;

    f16x8 a0[8], a1[8];
    #pragma unroll
    for (int s = 0; s < 8; ++s) {
        #pragma unroll
        for (int half = 0; half < 2; ++half) {
            int k4 = s * 4 + hw * 2 + half;
            float4 v = *(const float4*)&Zs[arow * 128 + ((k4 ^ (arow & 31)) << 2)];
            float xv[4] = {v.x, v.y, v.z, v.w};
            #pragma unroll
            for (int e = 0; e < 4; ++e) {
                _Float16 h = (_Float16)xv[e];
                a0[s][half * 4 + e] = h;
                a1[s][half * 4 + e] = (_Float16)(xv[e] - (float)h);
            }
        }
    }

    float best[16];
    int bidx[16];
    #pragma unroll
    for (int r = 0; r < 16; ++r) { best[r] = 3.4e38f; bidx[r] = 0; }

    for (int cb = 0; cb < 4; ++cb) {
        f32x16 acc[8];
        #pragma unroll
        for (int t = 0; t < 8; ++t)
            #pragma unroll
            for (int r = 0; r < 16; ++r) acc[t][r] = 0.f;

        #pragma unroll
        for (int s = 0; s < 8; ++s) {
            #pragma unroll
            for (int t = 0; t < 8; ++t) {
                int tg = cb * 8 + t;
                f16x8 bh = *(const f16x8*)(CBh + ((size_t)(tg * 8 + s) * 64 + l) * 8);
                f16x8 bl = *(const f16x8*)(CBl + ((size_t)(tg * 8 + s) * 64 + l) * 8);
                acc[t] = __builtin_amdgcn_mfma_f32_32x32x16_f16(a0[s], bh, acc[t], 0, 0, 0);
                acc[t] = __builtin_amdgcn_mfma_f32_32x32x16_f16(a0[s], bl, acc[t], 0, 0, 0);
                acc[t] = __builtin_amdgcn_mfma_f32_32x32x16_f16(a1[s], bh, acc[t], 0, 0, 0);
            }
        }

        float cnv[8];
        #pragma unroll
        for (int t = 0; t < 8; ++t) cnv[t] = cn[cb * 256 + t * 32 + col];

        #pragma unroll
        for (int reg = 0; reg < 16; ++reg) {
            #pragma unroll
            for (int t = 0; t < 8; ++t) {
                float d = cnv[t] - 2.f * acc[t][reg];
                int gi = cb * 256 + t * 32 + col;
                if (d < best[reg]) { best[reg] = d; bidx[reg] = gi; }
            }
        }
    }

    #pragma unroll
    for (int reg = 0; reg < 16; ++reg) {
        float bv_ = best[reg];
        int bi_ = bidx[reg];
        #pragma unroll
        for (int off = 1; off < 32; off <<= 1) {
            float ov = __shfl_xor(bv_, off, 64);
            int   oi = __shfl_xor(bi_, off, 64);
            if (ov < bv_ || (ov == bv_ && oi < bi_)) { bv_ = ov; bi_ = oi; }
        }
        if (col == 0) {
            int mloc = 32 * w + (reg & 3) + 8 * (reg >> 2) + 4 * hw;
            idx_s[mloc] = bi_;
            out[OFF_IDX + rowbase + mloc] = (float)bi_;
        }
    }
    __syncthreads();

    float ls = 0.f;
    #pragma unroll 8
    for (int i = 0; i < 64; ++i) {
        int row = 2 * i + rhalf;
        float z = Zs[row * 128 + (((a >> 2) ^ (row & 31)) << 2) + (a & 3)];
        int ci = idx_s[row];
        float q = CB[(size_t)ci * ACT + a];
        float diff = z - q;
        size_t m = (size_t)(rowbase + row);
        out[OFF_QS + m * ACT + a] = z + (q - z);
        out[OFF_AV + m * ACT + a] = diff;
        ls = fmaf(diff, diff, ls);
    }
    #pragma unroll
    for (int off = 32; off; off >>= 1) ls += __shfl_xor(ls, off, 64);
    if (l == 0) red[w] = ls;
    __syncthreads();
    if (tid == 0) atomicAdd(losss, red[0] + red[1] + red[2] + red[3]);
}

__global__ void k_losses(const float* __restrict__ losss, float* __restrict__ out)
{
    float v = *losss * (1.f / 6094848.f);
    out[OFF_QL] = v;
    out[OFF_CL] = v;
}

extern "C" void kernel_launch(void* const* d_in, const int* in_sizes, int n_in,
                              void* d_out, int out_size, void* d_ws, size_t ws_size,
                              hipStream_t stream)
{
    const float* slots = (const float*)d_in[0];
    const float* noise = (const float*)d_in[1];
    const float* W1    = (const float*)d_in[2];
    const float* b1    = (const float*)d_in[3];
    const float* ln_g  = (const float*)d_in[4];
    const float* ln_b  = (const float*)d_in[5];
    const float* W2    = (const float*)d_in[6];
    const float* b2    = (const float*)d_in[7];
    const float* Wm    = (const float*)d_in[8];
    const float* bm    = (const float*)d_in[9];
    const float* Wv    = (const float*)d_in[10];
    const float* bv    = (const float*)d_in[11];
    const float* CB    = (const float*)d_in[12];
    float* out = (float*)d_out;
    float* ws  = (float*)d_ws;

    float* MT    = ws + WS_MT;
    float* VT    = ws + WS_VT;
    float* cn    = ws + WS_CN;
    float* losss = ws + WS_LOSS;

    _Float16* Xh  = (_Float16*)(ws + WS_XH);
    _Float16* Xl  = (_Float16*)(ws + WS_XL);
    _Float16* W1h = (_Float16*)(ws + WS_W1H);
    _Float16* W1l = (_Float16*)(ws + WS_W1L);
    _Float16* W2h = (_Float16*)(ws + WS_W2H);
    _Float16* W2l = (_Float16*)(ws + WS_W2L);
    _Float16* Wmh = (_Float16*)(ws + WS_WMH);
    _Float16* Wml = (_Float16*)(ws + WS_WML);
    _Float16* Wvh = (_Float16*)(ws + WS_WVH);
    _Float16* Wvl = (_Float16*)(ws + WS_WVL);
    _Float16* CBh = (_Float16*)(ws + WS_CBH);
    _Float16* CBl = (_Float16*)(ws + WS_CBL);

    hipLaunchKernelGGL(k_packall, dim3(8964), dim3(256), 0, stream,
                       W1, W2, Wm, Wv, CB, slots,
                       W1h, W1l, W2h, W2l, Wmh, Wml, Wvh, Wvl, CBh, CBl,
                       Xh, Xl, cn, losss);
    hipLaunchKernelGGL(k_encoder_mfma, dim3(R_ROWS/32), dim3(1024), 0, stream,
                       Xh, Xl, b1, ln_g, ln_b, b2, bm, bv,
                       W1h, W1l, W2h, W2l, Wmh, Wml, Wvh, Wvl, MT, VT);
    hipLaunchKernelGGL(k_vqfused, dim3(M_ROWS/128), dim3(256), 0, stream,
                       MT, VT, noise, CBh, CBl, cn, CB, out, losss);
    hipLaunchKernelGGL(k_losses, dim3(1), dim3(1), 0, stream, losss, out);
}